// Round 2
// baseline (298.171 us; speedup 1.0000x reference)
//
#include <hip/hip_runtime.h>
#include <cmath>
#include <stdint.h>

// ---------------------------------------------------------------------------
// AttentionLayer: att = softmax((q@W1+b1) @ (k@W2+b2)^T / sqrt(Sk)) @ v
// B=4, SQ=SK=2048, D=UNITS=1024, fp32 in/out, bf16 MFMA internally.
// R6: same 256x256 8-phase engine as R5, but vmcnt checks fixed:
//     4x vmcnt(10) per iteration (tails of P2/P4/P6/P8) instead of
//     2x vmcnt(6). Each reading phase now only demands units staged
//     >=5 phases earlier (~2000 cyc slack) instead of 3 (~900 cyc),
//     so stage-latency no longer convoys the 8 barrier-locked waves.
// ---------------------------------------------------------------------------

typedef short short8 __attribute__((ext_vector_type(8)));
typedef float f32x4 __attribute__((ext_vector_type(4)));
typedef __bf16 bf16x8 __attribute__((ext_vector_type(8)));

typedef __attribute__((address_space(3))) void lds_void;
typedef __attribute__((address_space(1))) void gbl_void;

__device__ __forceinline__ unsigned short f2b(float x) {
    unsigned u = __builtin_bit_cast(unsigned, x);
    u += 0x7fffu + ((u >> 16) & 1u);
    return (unsigned short)(u >> 16);
}

// ---------------------------------------------------------------------------
// Fused prep: z = 0..3 v-batch transpose, 4..5 W1/W2 transpose,
//             6..7 q cast, 8..9 k cast.  grid (64, 32, 10) x 256 thr.
// ---------------------------------------------------------------------------
__global__ void prep_kernel(const float* __restrict__ q,
                            const float* __restrict__ k,
                            const float* __restrict__ v,
                            const float* __restrict__ W1,
                            const float* __restrict__ W2,
                            unsigned short* __restrict__ qbf,
                            unsigned short* __restrict__ kbf,
                            unsigned short* __restrict__ vT,
                            unsigned short* __restrict__ W1t,
                            unsigned short* __restrict__ W2t) {
    __shared__ float tile[32][33];
    const int bz = blockIdx.z;
    const int t = threadIdx.x;

    if (bz >= 6) {
        // ---- cast path: 2048 elems per block ----
        const float* in = (bz < 8) ? q : k;
        unsigned short* out = (bz < 8) ? qbf : kbf;
        const long zi = (bz - 6) & 1;
        const long fb = zi * 2048 + blockIdx.y * 64 + blockIdx.x;
        const long i = (fb * 256 + t) * 8;
        float4 a = *(const float4*)(in + i);
        float4 b = *(const float4*)(in + i + 4);
        union { short8 v8; unsigned short u[8]; } r;
        r.u[0] = f2b(a.x); r.u[1] = f2b(a.y); r.u[2] = f2b(a.z); r.u[3] = f2b(a.w);
        r.u[4] = f2b(b.x); r.u[5] = f2b(b.y); r.u[6] = f2b(b.z); r.u[7] = f2b(b.w);
        *(short8*)(out + i) = r.v8;
        return;
    }

    // ---- transpose path ----
    const float* in;
    unsigned short* out;
    int R, C;
    if (bz < 4) {
        R = 2048; C = 1024;
        in = v + (long)bz * R * C;
        out = vT + (long)bz * R * C;
    } else {
        R = 1024; C = 1024;
        if (blockIdx.x >= 32) return;
        in = (bz == 4) ? W1 : W2;
        out = (bz == 4) ? W1t : W2t;
    }
    const int rt = blockIdx.x * 32, ct = blockIdx.y * 32;
    {
        int r = t >> 3, c4 = (t & 7) * 4;
        float4 a = *(const float4*)(in + (long)(rt + r) * C + ct + c4);
        tile[r][c4 + 0] = a.x; tile[r][c4 + 1] = a.y;
        tile[r][c4 + 2] = a.z; tile[r][c4 + 3] = a.w;
    }
    __syncthreads();
    {
        int c = t >> 3, rg = (t & 7) * 4;
        ushort4 o;
        o.x = f2b(tile[rg + 0][c]); o.y = f2b(tile[rg + 1][c]);
        o.z = f2b(tile[rg + 2][c]); o.w = f2b(tile[rg + 3][c]);
        *(ushort4*)(out + (long)(ct + c) * R + rt + rg) = o;
    }
}

// ---------------------------------------------------------------------------
// bf16 GEMM: C[M][N] = A[M][K] * Bt[N][K]^T
// 256x256 tile, BK=64, 512 thr = 8 waves (2Mx4N), 8-phase counted-vmcnt.
// LDS [buf][khalf][256 rows][4 chunks x 8 bf16]; swizzle: phys_chunk =
// logical ^ ((row>>1)&3)  (inverse applied to per-lane GLOBAL source so the
// global_load_lds destination stays linear — both-sides-or-neither rule).
// Staging unit = one khalf of A or B (16 KB = 2 loads/thread), staged at
// the earliest phase its slot frees:
//   P1:Todd.B1  P2:Tev.A0  P3:Tev.B0  P4:Tev.A1  P5:Tev.B1
//   P6:Todd.A0  P7:Todd.B0  P8:Todd.A1      (Tev/Todd = next even/odd tile)
// First-read deadlines are all 6-7 phases after staging; the four
// vmcnt(10) checks (tails of P2/P4/P6/P8) each demand only the units the
// NEXT two phases read -> uniform 5-phase issue->check slack.
// MODE 0: bf16 out, + bias (bias1 when bz==1)
// MODE 1: bf16 out = exp(acc*scale), atomicAdd per-row sums into rowsum
// MODE 2: fp32 out = acc / rowsum[row]
// ---------------------------------------------------------------------------

#define BARRIER() do { asm volatile("" ::: "memory"); \
    __builtin_amdgcn_s_barrier(); \
    asm volatile("" ::: "memory"); } while (0)

#define VMC10 asm volatile("s_waitcnt vmcnt(10)" ::: "memory")
#define NOPSTMT do {} while (0)

#define STG(P0, P1, LBASE, KO) do { \
    const long ko_ = (KO); \
    __builtin_amdgcn_global_load_lds((gbl_void*)((P0) + ko_), \
        (lds_void*)((LBASE) + stgoff), 16, 0, 0); \
    __builtin_amdgcn_global_load_lds((gbl_void*)((P1) + ko_), \
        (lds_void*)((LBASE) + stgoff + 4096), 16, 0, 0); \
} while (0)

#define KOFF(T_, KH_) ((long)((((T_) < nTile) ? (T_) : ((T_) - nTile)) * 64 + (KH_) * 32))

#define LDA_(BUF, KH, I_) __builtin_bit_cast(bf16x8, \
    *(const short8*)(&As[BUF][KH][aoff + (I_) * 512]))
#define LDB_(BUF, KH, J_) __builtin_bit_cast(bf16x8, \
    *(const short8*)(&Bs[BUF][KH][boff + (J_) * 512]))

#define MFMA_PAIR(JA, JB) do { \
    _Pragma("unroll") \
    for (int i_ = 0; i_ < 8; i_++) { \
        acc[i_][JA] = __builtin_amdgcn_mfma_f32_16x16x32_bf16(a[i_], b[JA], acc[i_][JA], 0, 0, 0); \
        acc[i_][JB] = __builtin_amdgcn_mfma_f32_16x16x32_bf16(a[i_], b[JB], acc[i_][JB], 0, 0, 0); \
    } \
} while (0)

#define PHASE_A(BUF, KH, STAGE_STMT, TAIL_STMT) do { \
    _Pragma("unroll") \
    for (int i_ = 0; i_ < 8; i_++) a[i_] = LDA_(BUF, KH, i_); \
    b[0] = LDB_(BUF, KH, 0); \
    b[1] = LDB_(BUF, KH, 1); \
    STAGE_STMT; \
    BARRIER(); \
    __builtin_amdgcn_s_setprio(1); \
    MFMA_PAIR(0, 1); \
    __builtin_amdgcn_s_setprio(0); \
    TAIL_STMT; \
    BARRIER(); \
} while (0)

#define PHASE_B(BUF, KH, STAGE_STMT, TAIL_STMT) do { \
    b[2] = LDB_(BUF, KH, 2); \
    b[3] = LDB_(BUF, KH, 3); \
    STAGE_STMT; \
    BARRIER(); \
    __builtin_amdgcn_s_setprio(1); \
    MFMA_PAIR(2, 3); \
    __builtin_amdgcn_s_setprio(0); \
    TAIL_STMT; \
    BARRIER(); \
} while (0)

template <int MODE>
__global__ __launch_bounds__(512, 2) void gemm_bt_kernel(
                               const unsigned short* __restrict__ A,
                               const unsigned short* __restrict__ Bt,
                               const float* __restrict__ bias0,
                               const float* __restrict__ bias1,
                               float* __restrict__ rowsum,
                               void* __restrict__ Cout,
                               int M, int N, int K,
                               float scale,
                               long sA, long sB, long sC) {
    // [buf][khalf][256 rows * 32 bf16] = 4 x 16 KB per operand = 128 KiB total
    __shared__ __align__(16) unsigned short As[2][2][8192];
    __shared__ __align__(16) unsigned short Bs[2][2][8192];

    // ---- XCD-aware tile remap (bijective; all our grids have y*z % 8 == 0) ----
    int bx, by, bz;
    {
        const int nx = gridDim.x;
        const int Rt = gridDim.y * gridDim.z;
        if ((Rt & 7) == 0) {
            int flat = ((int)blockIdx.z * gridDim.y + blockIdx.y) * nx + blockIdx.x;
            int rpx = Rt >> 3;
            int c = flat & 7;
            int j = flat >> 3;
            bx = j / rpx;
            int yg = c * rpx + (j - bx * rpx);
            bz = yg / gridDim.y;
            by = yg - bz * gridDim.y;
        } else {
            bx = blockIdx.x; by = blockIdx.y; bz = blockIdx.z;
        }
    }

    A  += (long)bz * sA;
    Bt += (long)bz * sB;

    const int tid = threadIdx.x;
    const int lane = tid & 63;
    const int w = tid >> 6;            // wave 0..7
    const int wm = w >> 2, wn = w & 3; // 2Mx4N -> per-wave 128x64 output
    const int row0 = by * 256;
    const int col0 = bx * 256;

    // ---- staging addressing: one issue = 64 lanes x 16B = 16 rows of 32 bf16.
    // lane l -> row (l>>2), phys chunk (l&3); global logical chunk =
    // (l&3) ^ ((l>>3)&3)  == phys ^ ((row>>1)&3)   (inverse swizzle at source)
    const int srow = lane >> 2;
    const int sch  = (lane & 3) ^ ((lane >> 3) & 3);
    const unsigned short* pA0 = A  + (long)(row0 + w * 16 + srow) * K + sch * 8;
    const unsigned short* pA1 = pA0 + (long)128 * K;
    const unsigned short* pB0 = Bt + (long)(col0 + w * 16 + srow) * K + sch * 8;
    const unsigned short* pB1 = pB0 + (long)128 * K;
    const int stgoff = w * 512;        // wave-uniform LDS base within a unit

    // ---- fragment read addressing: row = (wm*128|wn*64) + f*16 + lr,
    // logical chunk q = lane>>4, phys = q ^ ((lr>>1)&3) -> 8 distinct 16B
    // bank positions, 2 lanes each (free 2-way; measured 0 conflicts)
    const int lr = lane & 15, quad = lane >> 4;
    const int rch  = (quad ^ ((lr >> 1) & 3)) * 8;
    const int aoff = (wm * 128 + lr) * 32 + rch;
    const int boff = (wn * 64  + lr) * 32 + rch;

    const int nTile = K >> 6;   // 64-wide K tiles
    const int nIter = K >> 7;   // 2 tiles per iteration

    f32x4 acc[8][4];
#pragma unroll
    for (int i = 0; i < 8; i++)
#pragma unroll
        for (int j = 0; j < 4; j++) acc[i][j] = f32x4{0.f, 0.f, 0.f, 0.f};
    bf16x8 a[8], b[4];

    // ---- prologue: stage T0 {A0,B0,A1,B1} + T1 {A0,B0,A1} = 14 loads/thread.
    // vmcnt(10) retires the oldest 4 = T0.A0,T0.B0 -- exactly what P1 reads.
    STG(pA0, pA1, &As[0][0][0], KOFF(0, 0));
    STG(pB0, pB1, &Bs[0][0][0], KOFF(0, 0));
    STG(pA0, pA1, &As[0][1][0], KOFF(0, 1));
    STG(pB0, pB1, &Bs[0][1][0], KOFF(0, 1));
    STG(pA0, pA1, &As[1][0][0], KOFF(1, 0));
    STG(pB0, pB1, &Bs[1][0][0], KOFF(1, 0));
    STG(pA0, pA1, &As[1][1][0], KOFF(1, 1));
    VMC10;
    BARRIER();

    // ---- main loop: iter computes T=2it (buf0, P1-4) and T=2it+1 (buf1, P5-8).
    // vmcnt(10) at tails of P2/P4/P6/P8: each retires exactly through the
    // units read by the next two phases (P3/P5/P7/next-P1 resp.), all of
    // which were staged >=5 phases before the check.
    // (final-iter overshoot tiles clamp to 0/1: harmless re-loads, never read)
    for (int it = 0; it < nIter; ++it) {
        const int t1 = 2 * it + 1, t2 = 2 * it + 2, t3 = 2 * it + 3;
        PHASE_A(0, 0, STG(pB0, pB1, &Bs[1][1][0], KOFF(t1, 1)), NOPSTMT);
        PHASE_B(0, 0, STG(pA0, pA1, &As[0][0][0], KOFF(t2, 0)), VMC10);
        PHASE_A(0, 1, STG(pB0, pB1, &Bs[0][0][0], KOFF(t2, 0)), NOPSTMT);
        PHASE_B(0, 1, STG(pA0, pA1, &As[0][1][0], KOFF(t2, 1)), VMC10);
        PHASE_A(1, 0, STG(pB0, pB1, &Bs[0][1][0], KOFF(t2, 1)), NOPSTMT);
        PHASE_B(1, 0, STG(pA0, pA1, &As[1][0][0], KOFF(t3, 0)), VMC10);
        PHASE_A(1, 1, STG(pB0, pB1, &Bs[1][0][0], KOFF(t3, 0)), NOPSTMT);
        PHASE_B(1, 1, STG(pA0, pA1, &As[1][1][0], KOFF(t3, 1)), VMC10);
    }
    // drain stray clamped stages before endpgm (LDS handed to next block)
    asm volatile("s_waitcnt vmcnt(0)" ::: "memory");

    // ---- epilogue (C/D layout: col = lane&15, row = quad*4 + reg) ----
    const long cbase = (long)bz * sC;

    if (MODE == 0) {
        const float* bp = (bz && bias1) ? bias1 : bias0;
#pragma unroll
        for (int j = 0; j < 4; j++) {
            const int gcol = col0 + wn * 64 + j * 16 + lr;
            const float bv = bp[gcol];
#pragma unroll
            for (int i = 0; i < 8; i++) {
                const int growb = row0 + wm * 128 + i * 16 + quad * 4;
#pragma unroll
                for (int r = 0; r < 4; r++) {
                    float val = acc[i][j][r] * scale + bv;
                    ((unsigned short*)Cout)[cbase + (long)(growb + r) * N + gcol] = f2b(val);
                }
            }
        }
    } else if (MODE == 1) {
        float psum[8][4];
#pragma unroll
        for (int i = 0; i < 8; i++)
#pragma unroll
            for (int r = 0; r < 4; r++) psum[i][r] = 0.f;
#pragma unroll
        for (int j = 0; j < 4; j++) {
            const int gcol = col0 + wn * 64 + j * 16 + lr;
#pragma unroll
            for (int i = 0; i < 8; i++) {
                const int growb = row0 + wm * 128 + i * 16 + quad * 4;
#pragma unroll
                for (int r = 0; r < 4; r++) {
                    float e = __expf(acc[i][j][r] * scale);
                    psum[i][r] += e;
                    ((unsigned short*)Cout)[cbase + (long)(growb + r) * N + gcol] = f2b(e);
                }
            }
        }
        // reduce across the 16 lr lanes (xor masks 1,2,4,8 keep quad bits)
#pragma unroll
        for (int i = 0; i < 8; i++)
#pragma unroll
            for (int r = 0; r < 4; r++) {
                float s = psum[i][r];
                s += __shfl_xor(s, 1);
                s += __shfl_xor(s, 2);
                s += __shfl_xor(s, 4);
                s += __shfl_xor(s, 8);
                if (lr == 0) {
                    const int grow = row0 + wm * 128 + i * 16 + quad * 4 + r;
                    atomicAdd(rowsum + (long)bz * M + grow, s);
                }
            }
    } else {  // MODE == 2
#pragma unroll
        for (int i = 0; i < 8; i++) {
            const int growb = row0 + wm * 128 + i * 16 + quad * 4;
#pragma unroll
            for (int r = 0; r < 4; r++) {
                const float inv = 1.0f / rowsum[(long)bz * M + growb + r];
#pragma unroll
                for (int j = 0; j < 4; j++) {
                    const int gcol = col0 + wn * 64 + j * 16 + lr;
                    ((float*)Cout)[cbase + (long)(growb + r) * N + gcol] =
                        acc[i][j][r] * inv;
                }
            }
        }
    }
}

// ---------------------------------------------------------------------------
extern "C" void kernel_launch(void* const* d_in, const int* in_sizes, int n_in,
                              void* d_out, int out_size, void* d_ws, size_t ws_size,
                              hipStream_t stream) {
    const float* q   = (const float*)d_in[0];
    const float* k   = (const float*)d_in[1];
    const float* v   = (const float*)d_in[2];
    const float* W1w = (const float*)d_in[3];
    const float* W1b = (const float*)d_in[4];
    const float* W2w = (const float*)d_in[5];
    const float* W2b = (const float*)d_in[6];
    float* out = (float*)d_out;

    const int B = 4, SQ = 2048, SK = 2048, D = 1024, U = 1024;
    char* ws = (char*)d_ws;
    const size_t MB = 1024 * 1024;
    unsigned short* qbf = (unsigned short*)(ws + 0);        // 16 MB
    unsigned short* kbf = (unsigned short*)(ws + 16 * MB);  // 16 MB
    unsigned short* vT  = (unsigned short*)(ws + 32 * MB);  // 16 MB [B][D][SK]
    unsigned short* W1t = (unsigned short*)(ws + 48 * MB);  // 2 MB  [U][D]
    unsigned short* W2t = (unsigned short*)(ws + 50 * MB);  // 2 MB  (dead after l1l2)
    unsigned short* l1  = (unsigned short*)(ws + 52 * MB);  // 16 MB [B*SQ][U]
    unsigned short* l2  = (unsigned short*)(ws + 68 * MB);  // 16 MB
    unsigned short* sc  = (unsigned short*)(ws + 0);        // 32 MB [B][SQ][SK]
    float* rowsum = (float*)(ws + 50 * MB);                 // 32 KB, reuses W2t slot

    // 1: all preprocessing (q/k cast, v/W1/W2 transpose)
    prep_kernel<<<dim3(64, 32, 10), 256, 0, stream>>>(
        q, k, v, W1w, W2w, qbf, kbf, vT, W1t, W2t);
    // 2: merged l1 = q@W1+b1 (bz=0), l2 = k@W2+b2 (bz=1)  (bf16 out)
    gemm_bt_kernel<0><<<dim3(U / 256, (B * SQ) / 256, 2), 512, 0, stream>>>(
        qbf, W1t, W1b, W2b, nullptr, l1, B * SQ, U, D, 1.0f,
        (long)8 * 1024 * 1024, (long)1024 * 1024, (long)8 * 1024 * 1024);
    // 3: zero rowsum (W2t now dead; stream order guarantees safety)
    hipMemsetAsync(rowsum, 0, (size_t)B * SQ * sizeof(float), stream);
    // 4: sc = exp(l1 @ l2^T / sqrt(SK)) bf16 + rowsum atomics
    const float invs = 1.0f / sqrtf((float)SK);
    gemm_bt_kernel<1><<<dim3(SK / 256, SQ / 256, B), 512, 0, stream>>>(
        l1, l2, nullptr, nullptr, rowsum, sc, SQ, SK, U, invs,
        (long)SQ * U, (long)SK * U, (long)SQ * SK);
    // 5: att = (sc @ vT^T) / rowsum[row]  (fp32 out)
    gemm_bt_kernel<2><<<dim3(D / 256, SQ / 256, B), 512, 0, stream>>>(
        sc, vT, nullptr, nullptr, rowsum, out, SQ, D, SK, 1.0f,
        (long)SQ * SK, (long)D * SK, (long)SQ * D);
}

// Round 3
// 291.254 us; speedup vs baseline: 1.0237x; 1.0237x over previous
//
#include <hip/hip_runtime.h>
#include <cmath>
#include <stdint.h>

// ---------------------------------------------------------------------------
// AttentionLayer: att = softmax((q@W1+b1) @ (k@W2+b2)^T / sqrt(Sk)) @ v
// B=4, SQ=SK=2048, D=UNITS=1024, fp32 in/out, bf16 MFMA internally.
// R7: same 256x256 8-phase engine + R6 vmcnt schedule, but ALL fragment
//     reads are inline-asm ds_read_b128 (invisible to alias analysis).
//     Theory: R5/R6 were slow because the compiler ordered C-level LDS
//     reads after outstanding global_load_lds to the same arrays and
//     inserted its own vmcnt drains per phase, defeating counted vmcnt.
//     Rule-18 compliance: barrier -> lgkmcnt(0) -> sched_barrier(0) -> MFMA.
// ---------------------------------------------------------------------------

typedef short short8 __attribute__((ext_vector_type(8)));
typedef float f32x4 __attribute__((ext_vector_type(4)));
typedef __bf16 bf16x8 __attribute__((ext_vector_type(8)));
typedef int i32x4 __attribute__((ext_vector_type(4)));

typedef __attribute__((address_space(3))) void lds_void;
typedef __attribute__((address_space(3))) unsigned short lds_ushort;
typedef __attribute__((address_space(1))) void gbl_void;

__device__ __forceinline__ unsigned short f2b(float x) {
    unsigned u = __builtin_bit_cast(unsigned, x);
    u += 0x7fffu + ((u >> 16) & 1u);
    return (unsigned short)(u >> 16);
}

// ---------------------------------------------------------------------------
// Fused prep: z = 0..3 v-batch transpose, 4..5 W1/W2 transpose,
//             6..7 q cast, 8..9 k cast.  grid (64, 32, 10) x 256 thr.
// ---------------------------------------------------------------------------
__global__ void prep_kernel(const float* __restrict__ q,
                            const float* __restrict__ k,
                            const float* __restrict__ v,
                            const float* __restrict__ W1,
                            const float* __restrict__ W2,
                            unsigned short* __restrict__ qbf,
                            unsigned short* __restrict__ kbf,
                            unsigned short* __restrict__ vT,
                            unsigned short* __restrict__ W1t,
                            unsigned short* __restrict__ W2t) {
    __shared__ float tile[32][33];
    const int bz = blockIdx.z;
    const int t = threadIdx.x;

    if (bz >= 6) {
        // ---- cast path: 2048 elems per block ----
        const float* in = (bz < 8) ? q : k;
        unsigned short* out = (bz < 8) ? qbf : kbf;
        const long zi = (bz - 6) & 1;
        const long fb = zi * 2048 + blockIdx.y * 64 + blockIdx.x;
        const long i = (fb * 256 + t) * 8;
        float4 a = *(const float4*)(in + i);
        float4 b = *(const float4*)(in + i + 4);
        union { short8 v8; unsigned short u[8]; } r;
        r.u[0] = f2b(a.x); r.u[1] = f2b(a.y); r.u[2] = f2b(a.z); r.u[3] = f2b(a.w);
        r.u[4] = f2b(b.x); r.u[5] = f2b(b.y); r.u[6] = f2b(b.z); r.u[7] = f2b(b.w);
        *(short8*)(out + i) = r.v8;
        return;
    }

    // ---- transpose path ----
    const float* in;
    unsigned short* out;
    int R, C;
    if (bz < 4) {
        R = 2048; C = 1024;
        in = v + (long)bz * R * C;
        out = vT + (long)bz * R * C;
    } else {
        R = 1024; C = 1024;
        if (blockIdx.x >= 32) return;
        in = (bz == 4) ? W1 : W2;
        out = (bz == 4) ? W1t : W2t;
    }
    const int rt = blockIdx.x * 32, ct = blockIdx.y * 32;
    {
        int r = t >> 3, c4 = (t & 7) * 4;
        float4 a = *(const float4*)(in + (long)(rt + r) * C + ct + c4);
        tile[r][c4 + 0] = a.x; tile[r][c4 + 1] = a.y;
        tile[r][c4 + 2] = a.z; tile[r][c4 + 3] = a.w;
    }
    __syncthreads();
    {
        int c = t >> 3, rg = (t & 7) * 4;
        ushort4 o;
        o.x = f2b(tile[rg + 0][c]); o.y = f2b(tile[rg + 1][c]);
        o.z = f2b(tile[rg + 2][c]); o.w = f2b(tile[rg + 3][c]);
        *(ushort4*)(out + (long)(ct + c) * R + rt + rg) = o;
    }
}

// ---------------------------------------------------------------------------
// bf16 GEMM: C[M][N] = A[M][K] * Bt[N][K]^T
// 256x256 tile, BK=64, 512 thr = 8 waves (2Mx4N), 8-phase counted-vmcnt.
// LDS [buf][khalf][256 rows][4 chunks x 8 bf16]; swizzle: phys_chunk =
// logical ^ ((row>>1)&3) (inverse pre-applied to the per-lane GLOBAL source).
// Staging unit = one khalf of A or B (16 KB = 2 loads/thread), staged at
// the earliest phase its slot frees:
//   P1:Todd.B1  P2:Tev.A0  P3:Tev.B0  P4:Tev.A1  P5:Tev.B1
//   P6:Todd.A0  P7:Todd.B0  P8:Todd.A1
// vmcnt(10) at tails of P2/P4/P6/P8 retires exactly the units the next two
// phases read, all staged >=5 phases before the check.
// Fragment reads = inline-asm ds_read_b128 so the compiler cannot see any
// alias with the outstanding global_load_lds and cannot insert drains.
// MODE 0: bf16 out, + bias (bias1 when bz==1)
// MODE 1: bf16 out = exp(acc*scale), atomicAdd per-row sums into rowsum
// MODE 2: fp32 out = acc / rowsum[row]
// ---------------------------------------------------------------------------

#define VMC10 asm volatile("s_waitcnt vmcnt(10)" ::: "memory")
#define NOPSTMT do {} while (0)

#define STG(P0, P1, LBASE, KO) do { \
    const long ko_ = (KO); \
    __builtin_amdgcn_global_load_lds((gbl_void*)((P0) + ko_), \
        (lds_void*)((LBASE) + stgoff), 16, 0, 0); \
    __builtin_amdgcn_global_load_lds((gbl_void*)((P1) + ko_), \
        (lds_void*)((LBASE) + stgoff + 4096), 16, 0, 0); \
} while (0)

#define KOFF(T_, KH_) ((long)((((T_) < nTile) ? (T_) : ((T_) - nTile)) * 64 + (KH_) * 32))

// inline-asm ds_read_b128: DST (bf16x8) <- LDS[ADDR + OFFLIT]
#define DSR(DST, ADDR, OFFLIT) do { \
    i32x4 t_; \
    asm volatile("ds_read_b128 %0, %1 offset:" OFFLIT \
                 : "=v"(t_) : "v"(ADDR)); \
    DST = __builtin_bit_cast(bf16x8, t_); \
} while (0)

#define MFMA8(BV, J_) do { \
    acc[0][J_] = __builtin_amdgcn_mfma_f32_16x16x32_bf16(a0, BV, acc[0][J_], 0, 0, 0); \
    acc[1][J_] = __builtin_amdgcn_mfma_f32_16x16x32_bf16(a1, BV, acc[1][J_], 0, 0, 0); \
    acc[2][J_] = __builtin_amdgcn_mfma_f32_16x16x32_bf16(a2, BV, acc[2][J_], 0, 0, 0); \
    acc[3][J_] = __builtin_amdgcn_mfma_f32_16x16x32_bf16(a3, BV, acc[3][J_], 0, 0, 0); \
    acc[4][J_] = __builtin_amdgcn_mfma_f32_16x16x32_bf16(a4, BV, acc[4][J_], 0, 0, 0); \
    acc[5][J_] = __builtin_amdgcn_mfma_f32_16x16x32_bf16(a5, BV, acc[5][J_], 0, 0, 0); \
    acc[6][J_] = __builtin_amdgcn_mfma_f32_16x16x32_bf16(a6, BV, acc[6][J_], 0, 0, 0); \
    acc[7][J_] = __builtin_amdgcn_mfma_f32_16x16x32_bf16(a7, BV, acc[7][J_], 0, 0, 0); \
} while (0)

// Phase A of a khalf: read 8 A-frags + B-frags 0,1; compute j=0,1.
#define PHASE_A(AB, BB, STAGE_STMT, TAIL_STMT) do { \
    DSR(a0, AB, "0");    DSR(a1, AB, "1024"); \
    DSR(a2, AB, "2048"); DSR(a3, AB, "3072"); \
    DSR(a4, AB, "4096"); DSR(a5, AB, "5120"); \
    DSR(a6, AB, "6144"); DSR(a7, AB, "7168"); \
    DSR(b0, BB, "0");    DSR(b1, BB, "1024"); \
    STAGE_STMT; \
    __builtin_amdgcn_s_barrier(); \
    asm volatile("s_waitcnt lgkmcnt(0)" ::: "memory"); \
    __builtin_amdgcn_sched_barrier(0); \
    __builtin_amdgcn_s_setprio(1); \
    MFMA8(b0, 0); \
    MFMA8(b1, 1); \
    __builtin_amdgcn_s_setprio(0); \
    TAIL_STMT; \
    __builtin_amdgcn_s_barrier(); \
} while (0)

// Phase B of a khalf: read B-frags 2,3 (A-frags already live); compute j=2,3.
#define PHASE_B(BB, STAGE_STMT, TAIL_STMT) do { \
    DSR(b2, BB, "2048"); DSR(b3, BB, "3072"); \
    STAGE_STMT; \
    __builtin_amdgcn_s_barrier(); \
    asm volatile("s_waitcnt lgkmcnt(0)" ::: "memory"); \
    __builtin_amdgcn_sched_barrier(0); \
    __builtin_amdgcn_s_setprio(1); \
    MFMA8(b2, 2); \
    MFMA8(b3, 3); \
    __builtin_amdgcn_s_setprio(0); \
    TAIL_STMT; \
    __builtin_amdgcn_s_barrier(); \
} while (0)

template <int MODE>
__global__ __launch_bounds__(512, 2) void gemm_bt_kernel(
                               const unsigned short* __restrict__ A,
                               const unsigned short* __restrict__ Bt,
                               const float* __restrict__ bias0,
                               const float* __restrict__ bias1,
                               float* __restrict__ rowsum,
                               void* __restrict__ Cout,
                               int M, int N, int K,
                               float scale,
                               long sA, long sB, long sC) {
    // [buf][khalf][256 rows * 32 bf16] = 4 x 16 KB per operand = 128 KiB total
    __shared__ __align__(16) unsigned short As[2][2][8192];
    __shared__ __align__(16) unsigned short Bs[2][2][8192];

    // ---- XCD-aware tile remap (bijective; all our grids have y*z % 8 == 0) ----
    int bx, by, bz;
    {
        const int nx = gridDim.x;
        const int Rt = gridDim.y * gridDim.z;
        if ((Rt & 7) == 0) {
            int flat = ((int)blockIdx.z * gridDim.y + blockIdx.y) * nx + blockIdx.x;
            int rpx = Rt >> 3;
            int c = flat & 7;
            int j = flat >> 3;
            bx = j / rpx;
            int yg = c * rpx + (j - bx * rpx);
            bz = yg / gridDim.y;
            by = yg - bz * gridDim.y;
        } else {
            bx = blockIdx.x; by = blockIdx.y; bz = blockIdx.z;
        }
    }

    A  += (long)bz * sA;
    Bt += (long)bz * sB;

    const int tid = threadIdx.x;
    const int lane = tid & 63;
    const int w = tid >> 6;            // wave 0..7
    const int wm = w >> 2, wn = w & 3; // 2Mx4N -> per-wave 128x64 output
    const int row0 = by * 256;
    const int col0 = bx * 256;

    // ---- staging addressing: one issue = 64 lanes x 16B = 16 rows of 32 bf16.
    // lane l -> row (l>>2), phys chunk (l&3); global logical chunk =
    // (l&3) ^ ((l>>3)&3)  == phys ^ ((row>>1)&3)   (inverse swizzle at source)
    const int srow = lane >> 2;
    const int sch  = (lane & 3) ^ ((lane >> 3) & 3);
    const unsigned short* pA0 = A  + (long)(row0 + w * 16 + srow) * K + sch * 8;
    const unsigned short* pA1 = pA0 + (long)128 * K;
    const unsigned short* pB0 = Bt + (long)(col0 + w * 16 + srow) * K + sch * 8;
    const unsigned short* pB1 = pB0 + (long)128 * K;
    const int stgoff = w * 512;        // wave-uniform LDS base within a unit

    // ---- fragment read addressing: row = (wm*128|wn*64) + f*16 + lr,
    // logical chunk q = lane>>4, phys = q ^ ((lr>>1)&3) -> 8 distinct 16B
    // bank positions, 2 lanes each (free 2-way; measured 0 conflicts)
    const int lr = lane & 15, quad = lane >> 4;
    const int rch  = (quad ^ ((lr >> 1) & 3)) * 8;
    const int aoff = (wm * 128 + lr) * 32 + rch;   // ushort units
    const int boff = (wn * 64  + lr) * 32 + rch;

    // 32-bit LDS byte addresses per unit (addrspace(3) value == LDS offset)
    const unsigned asBase = (unsigned)(unsigned long long)(lds_ushort*)&As[0][0][0];
    const unsigned bsBase = (unsigned)(unsigned long long)(lds_ushort*)&Bs[0][0][0];
    const unsigned aA00 = asBase + (unsigned)(aoff * 2);
    const unsigned aA01 = aA00 + 16384u;
    const unsigned aA10 = aA00 + 32768u;
    const unsigned aA11 = aA00 + 49152u;
    const unsigned bA00 = bsBase + (unsigned)(boff * 2);
    const unsigned bA01 = bA00 + 16384u;
    const unsigned bA10 = bA00 + 32768u;
    const unsigned bA11 = bA00 + 49152u;

    const int nTile = K >> 6;   // 64-wide K tiles
    const int nIter = K >> 7;   // 2 tiles per iteration

    f32x4 acc[8][4];
#pragma unroll
    for (int i = 0; i < 8; i++)
#pragma unroll
        for (int j = 0; j < 4; j++) acc[i][j] = f32x4{0.f, 0.f, 0.f, 0.f};
    bf16x8 a0, a1, a2, a3, a4, a5, a6, a7, b0, b1, b2, b3;

    // ---- prologue: stage T0 {A0,B0,A1,B1} + T1 {A0,B0,A1} = 14 loads/thread.
    // vmcnt(10) retires the oldest 4 = T0.A0,T0.B0 -- exactly what P1 reads.
    STG(pA0, pA1, &As[0][0][0], KOFF(0, 0));
    STG(pB0, pB1, &Bs[0][0][0], KOFF(0, 0));
    STG(pA0, pA1, &As[0][1][0], KOFF(0, 1));
    STG(pB0, pB1, &Bs[0][1][0], KOFF(0, 1));
    STG(pA0, pA1, &As[1][0][0], KOFF(1, 0));
    STG(pB0, pB1, &Bs[1][0][0], KOFF(1, 0));
    STG(pA0, pA1, &As[1][1][0], KOFF(1, 1));
    VMC10;
    __builtin_amdgcn_s_barrier();

    // ---- main loop: iter computes T=2it (buf0, P1-4) and T=2it+1 (buf1, P5-8).
    // (final-iter overshoot tiles clamp to 0/1: harmless re-loads, never read)
    for (int it = 0; it < nIter; ++it) {
        const int t1 = 2 * it + 1, t2 = 2 * it + 2, t3 = 2 * it + 3;
        PHASE_A(aA00, bA00, STG(pB0, pB1, &Bs[1][1][0], KOFF(t1, 1)), NOPSTMT);
        PHASE_B(bA00,       STG(pA0, pA1, &As[0][0][0], KOFF(t2, 0)), VMC10);
        PHASE_A(aA01, bA01, STG(pB0, pB1, &Bs[0][0][0], KOFF(t2, 0)), NOPSTMT);
        PHASE_B(bA01,       STG(pA0, pA1, &As[0][1][0], KOFF(t2, 1)), VMC10);
        PHASE_A(aA10, bA10, STG(pB0, pB1, &Bs[0][1][0], KOFF(t2, 1)), NOPSTMT);
        PHASE_B(bA10,       STG(pA0, pA1, &As[1][0][0], KOFF(t3, 0)), VMC10);
        PHASE_A(aA11, bA11, STG(pB0, pB1, &Bs[1][0][0], KOFF(t3, 0)), NOPSTMT);
        PHASE_B(bA11,       STG(pA0, pA1, &As[1][1][0], KOFF(t3, 1)), VMC10);
    }
    // drain stray clamped stages before epilogue stores
    asm volatile("s_waitcnt vmcnt(0)" ::: "memory");

    // ---- epilogue (C/D layout: col = lane&15, row = quad*4 + reg) ----
    const long cbase = (long)bz * sC;

    if (MODE == 0) {
        const float* bp = (bz && bias1) ? bias1 : bias0;
#pragma unroll
        for (int j = 0; j < 4; j++) {
            const int gcol = col0 + wn * 64 + j * 16 + lr;
            const float bv = bp[gcol];
#pragma unroll
            for (int i = 0; i < 8; i++) {
                const int growb = row0 + wm * 128 + i * 16 + quad * 4;
#pragma unroll
                for (int r = 0; r < 4; r++) {
                    float val = acc[i][j][r] * scale + bv;
                    ((unsigned short*)Cout)[cbase + (long)(growb + r) * N + gcol] = f2b(val);
                }
            }
        }
    } else if (MODE == 1) {
        float psum[8][4];
#pragma unroll
        for (int i = 0; i < 8; i++)
#pragma unroll
            for (int r = 0; r < 4; r++) psum[i][r] = 0.f;
#pragma unroll
        for (int j = 0; j < 4; j++) {
            const int gcol = col0 + wn * 64 + j * 16 + lr;
#pragma unroll
            for (int i = 0; i < 8; i++) {
                const int growb = row0 + wm * 128 + i * 16 + quad * 4;
#pragma unroll
                for (int r = 0; r < 4; r++) {
                    float e = __expf(acc[i][j][r] * scale);
                    psum[i][r] += e;
                    ((unsigned short*)Cout)[cbase + (long)(growb + r) * N + gcol] = f2b(e);
                }
            }
        }
        // reduce across the 16 lr lanes (xor masks 1,2,4,8 keep quad bits)
#pragma unroll
        for (int i = 0; i < 8; i++)
#pragma unroll
            for (int r = 0; r < 4; r++) {
                float s = psum[i][r];
                s += __shfl_xor(s, 1);
                s += __shfl_xor(s, 2);
                s += __shfl_xor(s, 4);
                s += __shfl_xor(s, 8);
                if (lr == 0) {
                    const int grow = row0 + wm * 128 + i * 16 + quad * 4 + r;
                    atomicAdd(rowsum + (long)bz * M + grow, s);
                }
            }
    } else {  // MODE == 2
#pragma unroll
        for (int i = 0; i < 8; i++) {
            const int growb = row0 + wm * 128 + i * 16 + quad * 4;
#pragma unroll
            for (int r = 0; r < 4; r++) {
                const float inv = 1.0f / rowsum[(long)bz * M + growb + r];
#pragma unroll
                for (int j = 0; j < 4; j++) {
                    const int gcol = col0 + wn * 64 + j * 16 + lr;
                    ((float*)Cout)[cbase + (long)(growb + r) * N + gcol] =
                        acc[i][j][r] * inv;
                }
            }
        }
    }
}

// ---------------------------------------------------------------------------
extern "C" void kernel_launch(void* const* d_in, const int* in_sizes, int n_in,
                              void* d_out, int out_size, void* d_ws, size_t ws_size,
                              hipStream_t stream) {
    const float* q   = (const float*)d_in[0];
    const float* k   = (const float*)d_in[1];
    const float* v   = (const float*)d_in[2];
    const float* W1w = (const float*)d_in[3];
    const float* W1b = (const float*)d_in[4];
    const float* W2w = (const float*)d_in[5];
    const float* W2b = (const float*)d_in[6];
    float* out = (float*)d_out;

    const int B = 4, SQ = 2048, SK = 2048, D = 1024, U = 1024;
    char* ws = (char*)d_ws;
    const size_t MB = 1024 * 1024;
    unsigned short* qbf = (unsigned short*)(ws + 0);        // 16 MB
    unsigned short* kbf = (unsigned short*)(ws + 16 * MB);  // 16 MB
    unsigned short* vT  = (unsigned short*)(ws + 32 * MB);  // 16 MB [B][D][SK]
    unsigned short* W1t = (unsigned short*)(ws + 48 * MB);  // 2 MB  [U][D]
    unsigned short* W2t = (unsigned short*)(ws + 50 * MB);  // 2 MB  (dead after l1l2)
    unsigned short* l1  = (unsigned short*)(ws + 52 * MB);  // 16 MB [B*SQ][U]
    unsigned short* l2  = (unsigned short*)(ws + 68 * MB);  // 16 MB
    unsigned short* sc  = (unsigned short*)(ws + 0);        // 32 MB [B][SQ][SK]
    float* rowsum = (float*)(ws + 50 * MB);                 // 32 KB, reuses W2t slot

    // 1: all preprocessing (q/k cast, v/W1/W2 transpose)
    prep_kernel<<<dim3(64, 32, 10), 256, 0, stream>>>(
        q, k, v, W1w, W2w, qbf, kbf, vT, W1t, W2t);
    // 2: merged l1 = q@W1+b1 (bz=0), l2 = k@W2+b2 (bz=1)  (bf16 out)
    gemm_bt_kernel<0><<<dim3(U / 256, (B * SQ) / 256, 2), 512, 0, stream>>>(
        qbf, W1t, W1b, W2b, nullptr, l1, B * SQ, U, D, 1.0f,
        (long)8 * 1024 * 1024, (long)1024 * 1024, (long)8 * 1024 * 1024);
    // 3: zero rowsum (W2t now dead; stream order guarantees safety)
    hipMemsetAsync(rowsum, 0, (size_t)B * SQ * sizeof(float), stream);
    // 4: sc = exp(l1 @ l2^T / sqrt(SK)) bf16 + rowsum atomics
    const float invs = 1.0f / sqrtf((float)SK);
    gemm_bt_kernel<1><<<dim3(SK / 256, SQ / 256, B), 512, 0, stream>>>(
        l1, l2, nullptr, nullptr, rowsum, sc, SQ, SK, U, invs,
        (long)SQ * U, (long)SK * U, (long)SQ * SK);
    // 5: att = (sc @ vT^T) / rowsum[row]  (fp32 out)
    gemm_bt_kernel<2><<<dim3(D / 256, SQ / 256, B), 512, 0, stream>>>(
        sc, vT, nullptr, nullptr, rowsum, out, SQ, D, SK, 1.0f,
        (long)SQ * SK, (long)D * SK, (long)SQ * D);
}

// Round 4
// 267.403 us; speedup vs baseline: 1.1151x; 1.0892x over previous
//
#include <hip/hip_runtime.h>
#include <cmath>
#include <stdint.h>

// ---------------------------------------------------------------------------
// AttentionLayer: att = softmax((q@W1+b1) @ (k@W2+b2)^T / sqrt(Sk)) @ v
// B=4, SQ=SK=2048, D=UNITS=1024, fp32 in/out, bf16 MFMA internally.
// R8: revert to the proven R4 single-buffered 2-barrier engine.
//     Theory: R4's 128^2 tile demands ~52 B/cyc/CU of L2 operand traffic
//     (== the 56 B/cyc/CU L2 ceiling) -> L2-BW-bound at ~600 TF.
//     Fix: 256x128 tile (512 thr, 8 waves 4Mx2N, per-wave 64x64 = same
//     register footprint as R4), LDS 48 KB keeps 2-3 blocks/CU residency.
//     Intensity 64 -> 87 FLOP/B, L2 demand ~40 B/cyc/CU.
//     att GEMM (grid too small for 2/CU at BM=256) stays on the verbatim
//     R4 128^2 engine -- differential test of the L2 theory.
// ---------------------------------------------------------------------------

typedef short short8 __attribute__((ext_vector_type(8)));
typedef float f32x4 __attribute__((ext_vector_type(4)));
typedef __bf16 bf16x8 __attribute__((ext_vector_type(8)));

typedef __attribute__((address_space(3))) void lds_void;
typedef __attribute__((address_space(1))) void gbl_void;

__device__ __forceinline__ unsigned short f2b(float x) {
    unsigned u = __builtin_bit_cast(unsigned, x);
    u += 0x7fffu + ((u >> 16) & 1u);
    return (unsigned short)(u >> 16);
}

// ---------------------------------------------------------------------------
// Fused prep: z = 0..3 v-batch transpose, 4..5 W1/W2 transpose,
//             6..7 q cast, 8..9 k cast.  grid (64, 32, 10) x 256 thr.
// ---------------------------------------------------------------------------
__global__ void prep_kernel(const float* __restrict__ q,
                            const float* __restrict__ k,
                            const float* __restrict__ v,
                            const float* __restrict__ W1,
                            const float* __restrict__ W2,
                            unsigned short* __restrict__ qbf,
                            unsigned short* __restrict__ kbf,
                            unsigned short* __restrict__ vT,
                            unsigned short* __restrict__ W1t,
                            unsigned short* __restrict__ W2t) {
    __shared__ float tile[32][33];
    const int bz = blockIdx.z;
    const int t = threadIdx.x;

    if (bz >= 6) {
        // ---- cast path: 2048 elems per block ----
        const float* in = (bz < 8) ? q : k;
        unsigned short* out = (bz < 8) ? qbf : kbf;
        const long zi = (bz - 6) & 1;
        const long fb = zi * 2048 + blockIdx.y * 64 + blockIdx.x;
        const long i = (fb * 256 + t) * 8;
        float4 a = *(const float4*)(in + i);
        float4 b = *(const float4*)(in + i + 4);
        union { short8 v8; unsigned short u[8]; } r;
        r.u[0] = f2b(a.x); r.u[1] = f2b(a.y); r.u[2] = f2b(a.z); r.u[3] = f2b(a.w);
        r.u[4] = f2b(b.x); r.u[5] = f2b(b.y); r.u[6] = f2b(b.z); r.u[7] = f2b(b.w);
        *(short8*)(out + i) = r.v8;
        return;
    }

    // ---- transpose path ----
    const float* in;
    unsigned short* out;
    int R, C;
    if (bz < 4) {
        R = 2048; C = 1024;
        in = v + (long)bz * R * C;
        out = vT + (long)bz * R * C;
    } else {
        R = 1024; C = 1024;
        if (blockIdx.x >= 32) return;
        in = (bz == 4) ? W1 : W2;
        out = (bz == 4) ? W1t : W2t;
    }
    const int rt = blockIdx.x * 32, ct = blockIdx.y * 32;
    {
        int r = t >> 3, c4 = (t & 7) * 4;
        float4 a = *(const float4*)(in + (long)(rt + r) * C + ct + c4);
        tile[r][c4 + 0] = a.x; tile[r][c4 + 1] = a.y;
        tile[r][c4 + 2] = a.z; tile[r][c4 + 3] = a.w;
    }
    __syncthreads();
    {
        int c = t >> 3, rg = (t & 7) * 4;
        ushort4 o;
        o.x = f2b(tile[rg + 0][c]); o.y = f2b(tile[rg + 1][c]);
        o.z = f2b(tile[rg + 2][c]); o.w = f2b(tile[rg + 3][c]);
        *(ushort4*)(out + (long)(ct + c) * R + rt + rg) = o;
    }
}

__device__ __forceinline__ void load16_to_lds(const unsigned short* g,
                                              unsigned short* l) {
    __builtin_amdgcn_global_load_lds((gbl_void*)g, (lds_void*)l, 16, 0, 0);
}

// ---------------------------------------------------------------------------
// 256x128 bf16 GEMM: C[M][N] = A[M][K] * Bt[N][K]^T, BK=64 (48 KB LDS),
// 512 thr = 8 waves (4Mx2N), each wave 4x4 of 16x16x32 MFMA per sub-k
// (per-wave 64x64 output -- identical register footprint to the R4 engine).
// LDS XOR swizzle (phys chunk = logical ^ (row&7)); XCD-stripe block remap.
// Single-buffered 2-barrier loop; latency hidden by 2-3 blocks/CU residency.
// MODE 0: bf16 out, + bias (bias1 used when bz==1 -- merged l1/l2)
// MODE 1: bf16 out = exp(acc*scale), atomicAdd per-row sums into rowsum
// MODE 2: fp32 out = acc / rowsum[row]
// ---------------------------------------------------------------------------
template <int MODE>
__global__ __launch_bounds__(512, 4) void gemm256_kernel(
                               const unsigned short* __restrict__ A,
                               const unsigned short* __restrict__ Bt,
                               const float* __restrict__ bias0,
                               const float* __restrict__ bias1,
                               float* __restrict__ rowsum,
                               void* __restrict__ Cout,
                               int M, int N, int K,
                               float scale,
                               long sA, long sB, long sC) {
    __shared__ __align__(16) unsigned short As[256 * 64];  // 32 KB
    __shared__ __align__(16) unsigned short Bs[128 * 64];  // 16 KB

    // ---- XCD-aware tile remap (bijective) ----
    int bx, by, bz;
    {
        const int nx = gridDim.x;
        const int Rt = gridDim.y * gridDim.z;
        if ((Rt & 7) == 0) {
            int flat = ((int)blockIdx.z * gridDim.y + blockIdx.y) * nx + blockIdx.x;
            int rpx = Rt >> 3;
            int c = flat & 7;
            int j = flat >> 3;
            bx = j / rpx;
            int yg = c * rpx + (j - bx * rpx);
            bz = yg / gridDim.y;
            by = yg - bz * gridDim.y;
        } else {
            bx = blockIdx.x; by = blockIdx.y; bz = blockIdx.z;
        }
    }

    A  += (long)bz * sA;
    Bt += (long)bz * sB;

    const int t = threadIdx.x;
    const int lane = t & 63;
    const int wave = t >> 6;               // 0..7
    const int wm = wave >> 1, wn = wave & 1;  // 4M x 2N
    const int row0 = by * 256;
    const int col0 = bx * 128;

    // staging: lane l -> row group l>>3 (8 rows/issue), phys chunk l&7;
    // source chunk XOR'd so phys = logical ^ (row&7)
    const int rS = lane >> 3;
    const int kOffS = ((lane & 7) ^ rS) * 8;
    const unsigned short* gA[4];
    unsigned short* lA[4];
    const unsigned short* gB[2];
    unsigned short* lB[2];
#pragma unroll
    for (int i = 0; i < 4; i++) {
        const int rowl = wave * 32 + i * 8;
        gA[i] = A + (long)(row0 + rowl + rS) * K + kOffS;
        lA[i] = As + rowl * 64;
    }
#pragma unroll
    for (int i = 0; i < 2; i++) {
        const int rowl = wave * 16 + i * 8;
        gB[i] = Bt + (long)(col0 + rowl + rS) * K + kOffS;
        lB[i] = Bs + rowl * 64;
    }

    const int lr = lane & 15;
    const int quad = lane >> 4;
    const int pc0 = (quad ^ (lr & 7)) * 8;
    const int pc1 = ((4 + quad) ^ (lr & 7)) * 8;

    f32x4 acc[4][4];
#pragma unroll
    for (int i = 0; i < 4; i++)
#pragma unroll
        for (int j = 0; j < 4; j++) acc[i][j] = f32x4{0.f, 0.f, 0.f, 0.f};

    for (int k0 = 0; k0 < K; k0 += 64) {
#pragma unroll
        for (int i = 0; i < 4; i++) load16_to_lds(gA[i] + k0, lA[i]);
#pragma unroll
        for (int i = 0; i < 2; i++) load16_to_lds(gB[i] + k0, lB[i]);
        __syncthreads();

#pragma unroll
        for (int ks = 0; ks < 2; ks++) {
            const int pc = ks ? pc1 : pc0;
            bf16x8 a[4], b[4];
#pragma unroll
            for (int i = 0; i < 4; i++) {
                a[i] = __builtin_bit_cast(bf16x8,
                    *(const short8*)(As + (wm * 64 + i * 16 + lr) * 64 + pc));
                b[i] = __builtin_bit_cast(bf16x8,
                    *(const short8*)(Bs + (wn * 64 + i * 16 + lr) * 64 + pc));
            }
#pragma unroll
            for (int i = 0; i < 4; i++)
#pragma unroll
                for (int j = 0; j < 4; j++)
                    acc[i][j] = __builtin_amdgcn_mfma_f32_16x16x32_bf16(
                        a[i], b[j], acc[i][j], 0, 0, 0);
        }
        __syncthreads();
    }

    // ---- epilogue (C/D layout: col = lane&15, row = quad*4 + reg) ----
    const long cbase = (long)bz * sC;

    if (MODE == 0) {
        const float* bp = (bz && bias1) ? bias1 : bias0;
#pragma unroll
        for (int j = 0; j < 4; j++) {
            const int gcol = col0 + wn * 64 + j * 16 + lr;
            const float bv = bp[gcol];
#pragma unroll
            for (int i = 0; i < 4; i++) {
                const int growb = row0 + wm * 64 + i * 16 + quad * 4;
#pragma unroll
                for (int r = 0; r < 4; r++) {
                    float val = acc[i][j][r] * scale + bv;
                    ((unsigned short*)Cout)[cbase + (long)(growb + r) * N + gcol] = f2b(val);
                }
            }
        }
    } else if (MODE == 1) {
        float psum[4][4];
#pragma unroll
        for (int i = 0; i < 4; i++)
#pragma unroll
            for (int r = 0; r < 4; r++) psum[i][r] = 0.f;
#pragma unroll
        for (int j = 0; j < 4; j++) {
            const int gcol = col0 + wn * 64 + j * 16 + lr;
#pragma unroll
            for (int i = 0; i < 4; i++) {
                const int growb = row0 + wm * 64 + i * 16 + quad * 4;
#pragma unroll
                for (int r = 0; r < 4; r++) {
                    float e = __expf(acc[i][j][r] * scale);
                    psum[i][r] += e;
                    ((unsigned short*)Cout)[cbase + (long)(growb + r) * N + gcol] = f2b(e);
                }
            }
        }
        // reduce across the 16 lr lanes (xor masks 1,2,4,8 keep quad bits)
#pragma unroll
        for (int i = 0; i < 4; i++)
#pragma unroll
            for (int r = 0; r < 4; r++) {
                float s = psum[i][r];
                s += __shfl_xor(s, 1);
                s += __shfl_xor(s, 2);
                s += __shfl_xor(s, 4);
                s += __shfl_xor(s, 8);
                if (lr == 0) {
                    const int grow = row0 + wm * 64 + i * 16 + quad * 4 + r;
                    atomicAdd(rowsum + (long)bz * M + grow, s);
                }
            }
    } else {  // MODE == 2
#pragma unroll
        for (int i = 0; i < 4; i++) {
            const int growb = row0 + wm * 64 + i * 16 + quad * 4;
#pragma unroll
            for (int r = 0; r < 4; r++) {
                const float inv = 1.0f / rowsum[(long)bz * M + growb + r];
#pragma unroll
                for (int j = 0; j < 4; j++) {
                    const int gcol = col0 + wn * 64 + j * 16 + lr;
                    ((float*)Cout)[cbase + (long)(growb + r) * N + gcol] =
                        acc[i][j][r] * inv;
                }
            }
        }
    }
}

// ---------------------------------------------------------------------------
// Verbatim R4 128x128 engine (proven 57 us/dispatch) -- used for the att
// GEMM, whose grid at BM=256 would drop to 1 block/CU.
// ---------------------------------------------------------------------------
template <int MODE>
__global__ void gemm128_kernel(const unsigned short* __restrict__ A,
                               const unsigned short* __restrict__ Bt,
                               const float* __restrict__ bias0,
                               const float* __restrict__ bias1,
                               float* __restrict__ rowsum,
                               void* __restrict__ Cout,
                               int M, int N, int K,
                               float scale,
                               long sA, long sB, long sC) {
    __shared__ __align__(16) unsigned short As[128 * 64];
    __shared__ __align__(16) unsigned short Bs[128 * 64];

    int bx, by, bz;
    {
        const int nx = gridDim.x;
        const int Rt = gridDim.y * gridDim.z;
        if ((Rt & 7) == 0) {
            int flat = ((int)blockIdx.z * gridDim.y + blockIdx.y) * nx + blockIdx.x;
            int rpx = Rt >> 3;
            int c = flat & 7;
            int j = flat >> 3;
            bx = j / rpx;
            int yg = c * rpx + (j - bx * rpx);
            bz = yg / gridDim.y;
            by = yg - bz * gridDim.y;
        } else {
            bx = blockIdx.x; by = blockIdx.y; bz = blockIdx.z;
        }
    }

    A  += (long)bz * sA;
    Bt += (long)bz * sB;

    const int t = threadIdx.x;
    const int lane = t & 63;
    const int wave = t >> 6;
    const int wm = wave >> 1, wn = wave & 1;
    const int row0 = by * 128;
    const int col0 = bx * 128;

    const int rS = lane >> 3;
    const int kOffS = ((lane & 7) ^ rS) * 8;
    const unsigned short* gA[4];
    const unsigned short* gB[4];
    unsigned short* lA[4];
    unsigned short* lB[4];
#pragma unroll
    for (int i = 0; i < 4; i++) {
        const int rowl = i * 32 + wave * 8 + rS;
        const int ldsrow = i * 32 + wave * 8;
        gA[i] = A  + (long)(row0 + rowl) * K + kOffS;
        gB[i] = Bt + (long)(col0 + rowl) * K + kOffS;
        lA[i] = As + ldsrow * 64;
        lB[i] = Bs + ldsrow * 64;
    }

    const int lr = lane & 15;
    const int quad = lane >> 4;
    const int pc0 = (quad ^ (lr & 7)) * 8;
    const int pc1 = ((4 + quad) ^ (lr & 7)) * 8;

    f32x4 acc[4][4];
#pragma unroll
    for (int i = 0; i < 4; i++)
#pragma unroll
        for (int j = 0; j < 4; j++) acc[i][j] = f32x4{0.f, 0.f, 0.f, 0.f};

    for (int k0 = 0; k0 < K; k0 += 64) {
#pragma unroll
        for (int i = 0; i < 4; i++) {
            load16_to_lds(gA[i] + k0, lA[i]);
            load16_to_lds(gB[i] + k0, lB[i]);
        }
        __syncthreads();

#pragma unroll
        for (int ks = 0; ks < 2; ks++) {
            const int pc = ks ? pc1 : pc0;
            bf16x8 a[4], b[4];
#pragma unroll
            for (int i = 0; i < 4; i++) {
                a[i] = __builtin_bit_cast(bf16x8,
                    *(const short8*)(As + (wm * 64 + i * 16 + lr) * 64 + pc));
                b[i] = __builtin_bit_cast(bf16x8,
                    *(const short8*)(Bs + (wn * 64 + i * 16 + lr) * 64 + pc));
            }
#pragma unroll
            for (int i = 0; i < 4; i++)
#pragma unroll
                for (int j = 0; j < 4; j++)
                    acc[i][j] = __builtin_amdgcn_mfma_f32_16x16x32_bf16(
                        a[i], b[j], acc[i][j], 0, 0, 0);
        }
        __syncthreads();
    }

    const long cbase = (long)bz * sC;

    if (MODE == 0) {
        const float* bp = (bz && bias1) ? bias1 : bias0;
#pragma unroll
        for (int j = 0; j < 4; j++) {
            const int gcol = col0 + wn * 64 + j * 16 + lr;
            const float bv = bp[gcol];
#pragma unroll
            for (int i = 0; i < 4; i++) {
                const int growb = row0 + wm * 64 + i * 16 + quad * 4;
#pragma unroll
                for (int r = 0; r < 4; r++) {
                    float val = acc[i][j][r] * scale + bv;
                    ((unsigned short*)Cout)[cbase + (long)(growb + r) * N + gcol] = f2b(val);
                }
            }
        }
    } else if (MODE == 1) {
        float psum[4][4];
#pragma unroll
        for (int i = 0; i < 4; i++)
#pragma unroll
            for (int r = 0; r < 4; r++) psum[i][r] = 0.f;
#pragma unroll
        for (int j = 0; j < 4; j++) {
            const int gcol = col0 + wn * 64 + j * 16 + lr;
#pragma unroll
            for (int i = 0; i < 4; i++) {
                const int growb = row0 + wm * 64 + i * 16 + quad * 4;
#pragma unroll
                for (int r = 0; r < 4; r++) {
                    float e = __expf(acc[i][j][r] * scale);
                    psum[i][r] += e;
                    ((unsigned short*)Cout)[cbase + (long)(growb + r) * N + gcol] = f2b(e);
                }
            }
        }
#pragma unroll
        for (int i = 0; i < 4; i++)
#pragma unroll
            for (int r = 0; r < 4; r++) {
                float s = psum[i][r];
                s += __shfl_xor(s, 1);
                s += __shfl_xor(s, 2);
                s += __shfl_xor(s, 4);
                s += __shfl_xor(s, 8);
                if (lr == 0) {
                    const int grow = row0 + wm * 64 + i * 16 + quad * 4 + r;
                    atomicAdd(rowsum + (long)bz * M + grow, s);
                }
            }
    } else {  // MODE == 2
#pragma unroll
        for (int i = 0; i < 4; i++) {
            const int growb = row0 + wm * 64 + i * 16 + quad * 4;
#pragma unroll
            for (int r = 0; r < 4; r++) {
                const float inv = 1.0f / rowsum[(long)bz * M + growb + r];
#pragma unroll
                for (int j = 0; j < 4; j++) {
                    const int gcol = col0 + wn * 64 + j * 16 + lr;
                    ((float*)Cout)[cbase + (long)(growb + r) * N + gcol] =
                        acc[i][j][r] * inv;
                }
            }
        }
    }
}

// ---------------------------------------------------------------------------
extern "C" void kernel_launch(void* const* d_in, const int* in_sizes, int n_in,
                              void* d_out, int out_size, void* d_ws, size_t ws_size,
                              hipStream_t stream) {
    const float* q   = (const float*)d_in[0];
    const float* k   = (const float*)d_in[1];
    const float* v   = (const float*)d_in[2];
    const float* W1w = (const float*)d_in[3];
    const float* W1b = (const float*)d_in[4];
    const float* W2w = (const float*)d_in[5];
    const float* W2b = (const float*)d_in[6];
    float* out = (float*)d_out;

    const int B = 4, SQ = 2048, SK = 2048, D = 1024, U = 1024;
    char* ws = (char*)d_ws;
    const size_t MB = 1024 * 1024;
    unsigned short* qbf = (unsigned short*)(ws + 0);        // 16 MB
    unsigned short* kbf = (unsigned short*)(ws + 16 * MB);  // 16 MB
    unsigned short* vT  = (unsigned short*)(ws + 32 * MB);  // 16 MB [B][D][SK]
    unsigned short* W1t = (unsigned short*)(ws + 48 * MB);  // 2 MB  [U][D]
    unsigned short* W2t = (unsigned short*)(ws + 50 * MB);  // 2 MB  (dead after l1l2)
    unsigned short* l1  = (unsigned short*)(ws + 52 * MB);  // 16 MB [B*SQ][U]
    unsigned short* l2  = (unsigned short*)(ws + 68 * MB);  // 16 MB
    unsigned short* sc  = (unsigned short*)(ws + 0);        // 32 MB [B][SQ][SK]
    float* rowsum = (float*)(ws + 50 * MB);                 // 32 KB, reuses W2t slot

    // 1: all preprocessing (q/k cast, v/W1/W2 transpose)
    prep_kernel<<<dim3(64, 32, 10), 256, 0, stream>>>(
        q, k, v, W1w, W2w, qbf, kbf, vT, W1t, W2t);
    // 2: merged l1 = q@W1+b1 (bz=0), l2 = k@W2+b2 (bz=1)  (bf16 out)
    gemm256_kernel<0><<<dim3(U / 128, (B * SQ) / 256, 2), 512, 0, stream>>>(
        qbf, W1t, W1b, W2b, nullptr, l1, B * SQ, U, D, 1.0f,
        (long)8 * 1024 * 1024, (long)1024 * 1024, (long)8 * 1024 * 1024);
    // 3: zero rowsum (W2t now dead; stream order guarantees safety)
    hipMemsetAsync(rowsum, 0, (size_t)B * SQ * sizeof(float), stream);
    // 4: sc = exp(l1 @ l2^T / sqrt(SK)) bf16 + rowsum atomics
    const float invs = 1.0f / sqrtf((float)SK);
    gemm256_kernel<1><<<dim3(SK / 128, SQ / 256, B), 512, 0, stream>>>(
        l1, l2, nullptr, nullptr, rowsum, sc, SQ, SK, U, invs,
        (long)SQ * U, (long)SK * U, (long)SQ * SK);
    // 5: att = (sc @ vT^T) / rowsum[row]  (fp32 out) -- proven 128^2 engine
    gemm128_kernel<2><<<dim3(D / 128, SQ / 128, B), 256, 0, stream>>>(
        sc, vT, nullptr, nullptr, rowsum, out, SQ, D, SK, 1.0f,
        (long)SQ * SK, (long)D * SK, (long)SQ * D);
}

// Round 5
// 265.515 us; speedup vs baseline: 1.1230x; 1.0071x over previous
//
#include <hip/hip_runtime.h>
#include <cmath>
#include <stdint.h>

// ---------------------------------------------------------------------------
// AttentionLayer: att = softmax((q@W1+b1) @ (k@W2+b2)^T / sqrt(Sk)) @ v
// B=4, SQ=SK=2048, D=UNITS=1024, fp32 in/out, bf16 MFMA internally.
// R9: GEMM engines frozen (R8: 256x128 for l1l2/score, 128^2 for att).
//     prep v2: 64x64 transpose tiles -> 16B/lane short8 stores (128B
//     segments) and 256B read segments; rowsum moved out of the W2t slot
//     and zeroed inside prep (stowaway blocks) -> memset dispatch removed.
// ---------------------------------------------------------------------------

typedef short short8 __attribute__((ext_vector_type(8)));
typedef float f32x4 __attribute__((ext_vector_type(4)));
typedef __bf16 bf16x8 __attribute__((ext_vector_type(8)));

typedef __attribute__((address_space(3))) void lds_void;
typedef __attribute__((address_space(1))) void gbl_void;

__device__ __forceinline__ unsigned short f2b(float x) {
    unsigned u = __builtin_bit_cast(unsigned, x);
    u += 0x7fffu + ((u >> 16) & 1u);
    return (unsigned short)(u >> 16);
}

// ---------------------------------------------------------------------------
// Fused prep v2: z = 0..3 v-batch transpose (64x64 tiles), 4..5 W1/W2
// transpose (+ rowsum zero stowaway on z=4), 6..7 q cast, 8..9 k cast.
// grid (64, 32, 10) x 256 thr.
// Transpose: read 4x float4/lane (256B segments), LDS float[64][65]
// (2-way max bank aliasing = free), write short8/lane (128B segments).
// ---------------------------------------------------------------------------
__global__ void prep_kernel(const float* __restrict__ q,
                            const float* __restrict__ k,
                            const float* __restrict__ v,
                            const float* __restrict__ W1,
                            const float* __restrict__ W2,
                            unsigned short* __restrict__ qbf,
                            unsigned short* __restrict__ kbf,
                            unsigned short* __restrict__ vT,
                            unsigned short* __restrict__ W1t,
                            unsigned short* __restrict__ W2t,
                            float* __restrict__ rs) {
    const int bz = blockIdx.z;
    const int t = threadIdx.x;

    if (bz >= 6) {
        // ---- cast path: 2048 elems per block (unchanged from R8) ----
        const float* in = (bz < 8) ? q : k;
        unsigned short* out = (bz < 8) ? qbf : kbf;
        const long zi = (bz - 6) & 1;
        const long fb = zi * 2048 + blockIdx.y * 64 + blockIdx.x;
        const long i = (fb * 256 + t) * 8;
        float4 a = *(const float4*)(in + i);
        float4 b = *(const float4*)(in + i + 4);
        union { short8 v8; unsigned short u[8]; } r;
        r.u[0] = f2b(a.x); r.u[1] = f2b(a.y); r.u[2] = f2b(a.z); r.u[3] = f2b(a.w);
        r.u[4] = f2b(b.x); r.u[5] = f2b(b.y); r.u[6] = f2b(b.z); r.u[7] = f2b(b.w);
        *(short8*)(out + i) = r.v8;
        return;
    }

    const int tid2 = blockIdx.y * 64 + blockIdx.x;   // 0..2047

    // ---- rowsum-zero stowaway: 32 idle blocks of the z=4 slice ----
    if (bz == 4 && tid2 >= 256 && tid2 < 288) {
        if (rs) rs[(tid2 - 256) * 256 + t] = 0.f;
        return;
    }

    // ---- transpose path: 64x64 tiles ----
    __shared__ float tile[64][65];
    const float* in;
    unsigned short* out;
    int R, C;
    if (bz < 4) {
        R = 2048; C = 1024;                 // v: 32 row-tiles x 16 col-tiles
        if (tid2 >= 512) return;
        in = v + (long)bz * R * C;
        out = vT + (long)bz * R * C;
    } else {
        R = 1024; C = 1024;                 // W: 16 x 16 tiles
        if (tid2 >= 256) return;
        in = (bz == 4) ? W1 : W2;
        out = (bz == 4) ? W1t : W2t;
    }
    const int rt = (tid2 >> 4) * 64;
    const int ct = (tid2 & 15) * 64;

    {
        const int rr = t >> 2;              // 0..63
        const int cb = (t & 3) * 16;        // 0,16,32,48
        const float* src = in + (long)(rt + rr) * C + ct + cb;
#pragma unroll
        for (int u = 0; u < 4; u++) {
            float4 a = *(const float4*)(src + 4 * u);
            tile[rr][cb + 4 * u + 0] = a.x;
            tile[rr][cb + 4 * u + 1] = a.y;
            tile[rr][cb + 4 * u + 2] = a.z;
            tile[rr][cb + 4 * u + 3] = a.w;
        }
    }
    __syncthreads();
    {
        const int cc = t >> 2;              // 0..63
        const int rb = (t & 3) * 16;        // 0,16,32,48
        unsigned short* dst = out + (long)(ct + cc) * R + rt + rb;
#pragma unroll
        for (int u = 0; u < 2; u++) {
            union { short8 v8; unsigned short us[8]; } o;
#pragma unroll
            for (int e = 0; e < 8; e++) o.us[e] = f2b(tile[rb + 8 * u + e][cc]);
            *(short8*)(dst + 8 * u) = o.v8;
        }
    }
}

__device__ __forceinline__ void load16_to_lds(const unsigned short* g,
                                              unsigned short* l) {
    __builtin_amdgcn_global_load_lds((gbl_void*)g, (lds_void*)l, 16, 0, 0);
}

// ---------------------------------------------------------------------------
// 256x128 bf16 GEMM: C[M][N] = A[M][K] * Bt[N][K]^T, BK=64 (48 KB LDS),
// 512 thr = 8 waves (4Mx2N), each wave 4x4 of 16x16x32 MFMA per sub-k.
// LDS XOR swizzle (phys chunk = logical ^ (row&7)); XCD-stripe block remap.
// Single-buffered 2-barrier loop; latency hidden by 2-3 blocks/CU residency.
// MODE 0: bf16 out, + bias (bias1 used when bz==1 -- merged l1/l2)
// MODE 1: bf16 out = exp(acc*scale), atomicAdd per-row sums into rowsum
// MODE 2: fp32 out = acc / rowsum[row]
// ---------------------------------------------------------------------------
template <int MODE>
__global__ __launch_bounds__(512, 4) void gemm256_kernel(
                               const unsigned short* __restrict__ A,
                               const unsigned short* __restrict__ Bt,
                               const float* __restrict__ bias0,
                               const float* __restrict__ bias1,
                               float* __restrict__ rowsum,
                               void* __restrict__ Cout,
                               int M, int N, int K,
                               float scale,
                               long sA, long sB, long sC) {
    __shared__ __align__(16) unsigned short As[256 * 64];  // 32 KB
    __shared__ __align__(16) unsigned short Bs[128 * 64];  // 16 KB

    // ---- XCD-aware tile remap (bijective) ----
    int bx, by, bz;
    {
        const int nx = gridDim.x;
        const int Rt = gridDim.y * gridDim.z;
        if ((Rt & 7) == 0) {
            int flat = ((int)blockIdx.z * gridDim.y + blockIdx.y) * nx + blockIdx.x;
            int rpx = Rt >> 3;
            int c = flat & 7;
            int j = flat >> 3;
            bx = j / rpx;
            int yg = c * rpx + (j - bx * rpx);
            bz = yg / gridDim.y;
            by = yg - bz * gridDim.y;
        } else {
            bx = blockIdx.x; by = blockIdx.y; bz = blockIdx.z;
        }
    }

    A  += (long)bz * sA;
    Bt += (long)bz * sB;

    const int t = threadIdx.x;
    const int lane = t & 63;
    const int wave = t >> 6;               // 0..7
    const int wm = wave >> 1, wn = wave & 1;  // 4M x 2N
    const int row0 = by * 256;
    const int col0 = bx * 128;

    // staging: lane l -> row group l>>3 (8 rows/issue), phys chunk l&7;
    // source chunk XOR'd so phys = logical ^ (row&7)
    const int rS = lane >> 3;
    const int kOffS = ((lane & 7) ^ rS) * 8;
    const unsigned short* gA[4];
    unsigned short* lA[4];
    const unsigned short* gB[2];
    unsigned short* lB[2];
#pragma unroll
    for (int i = 0; i < 4; i++) {
        const int rowl = wave * 32 + i * 8;
        gA[i] = A + (long)(row0 + rowl + rS) * K + kOffS;
        lA[i] = As + rowl * 64;
    }
#pragma unroll
    for (int i = 0; i < 2; i++) {
        const int rowl = wave * 16 + i * 8;
        gB[i] = Bt + (long)(col0 + rowl + rS) * K + kOffS;
        lB[i] = Bs + rowl * 64;
    }

    const int lr = lane & 15;
    const int quad = lane >> 4;
    const int pc0 = (quad ^ (lr & 7)) * 8;
    const int pc1 = ((4 + quad) ^ (lr & 7)) * 8;

    f32x4 acc[4][4];
#pragma unroll
    for (int i = 0; i < 4; i++)
#pragma unroll
        for (int j = 0; j < 4; j++) acc[i][j] = f32x4{0.f, 0.f, 0.f, 0.f};

    for (int k0 = 0; k0 < K; k0 += 64) {
#pragma unroll
        for (int i = 0; i < 4; i++) load16_to_lds(gA[i] + k0, lA[i]);
#pragma unroll
        for (int i = 0; i < 2; i++) load16_to_lds(gB[i] + k0, lB[i]);
        __syncthreads();

#pragma unroll
        for (int ks = 0; ks < 2; ks++) {
            const int pc = ks ? pc1 : pc0;
            bf16x8 a[4], b[4];
#pragma unroll
            for (int i = 0; i < 4; i++) {
                a[i] = __builtin_bit_cast(bf16x8,
                    *(const short8*)(As + (wm * 64 + i * 16 + lr) * 64 + pc));
                b[i] = __builtin_bit_cast(bf16x8,
                    *(const short8*)(Bs + (wn * 64 + i * 16 + lr) * 64 + pc));
            }
#pragma unroll
            for (int i = 0; i < 4; i++)
#pragma unroll
                for (int j = 0; j < 4; j++)
                    acc[i][j] = __builtin_amdgcn_mfma_f32_16x16x32_bf16(
                        a[i], b[j], acc[i][j], 0, 0, 0);
        }
        __syncthreads();
    }

    // ---- epilogue (C/D layout: col = lane&15, row = quad*4 + reg) ----
    const long cbase = (long)bz * sC;

    if (MODE == 0) {
        const float* bp = (bz && bias1) ? bias1 : bias0;
#pragma unroll
        for (int j = 0; j < 4; j++) {
            const int gcol = col0 + wn * 64 + j * 16 + lr;
            const float bv = bp[gcol];
#pragma unroll
            for (int i = 0; i < 4; i++) {
                const int growb = row0 + wm * 64 + i * 16 + quad * 4;
#pragma unroll
                for (int r = 0; r < 4; r++) {
                    float val = acc[i][j][r] * scale + bv;
                    ((unsigned short*)Cout)[cbase + (long)(growb + r) * N + gcol] = f2b(val);
                }
            }
        }
    } else if (MODE == 1) {
        float psum[4][4];
#pragma unroll
        for (int i = 0; i < 4; i++)
#pragma unroll
            for (int r = 0; r < 4; r++) psum[i][r] = 0.f;
#pragma unroll
        for (int j = 0; j < 4; j++) {
            const int gcol = col0 + wn * 64 + j * 16 + lr;
#pragma unroll
            for (int i = 0; i < 4; i++) {
                const int growb = row0 + wm * 64 + i * 16 + quad * 4;
#pragma unroll
                for (int r = 0; r < 4; r++) {
                    float e = __expf(acc[i][j][r] * scale);
                    psum[i][r] += e;
                    ((unsigned short*)Cout)[cbase + (long)(growb + r) * N + gcol] = f2b(e);
                }
            }
        }
        // reduce across the 16 lr lanes (xor masks 1,2,4,8 keep quad bits)
#pragma unroll
        for (int i = 0; i < 4; i++)
#pragma unroll
            for (int r = 0; r < 4; r++) {
                float s = psum[i][r];
                s += __shfl_xor(s, 1);
                s += __shfl_xor(s, 2);
                s += __shfl_xor(s, 4);
                s += __shfl_xor(s, 8);
                if (lr == 0) {
                    const int grow = row0 + wm * 64 + i * 16 + quad * 4 + r;
                    atomicAdd(rowsum + (long)bz * M + grow, s);
                }
            }
    } else {  // MODE == 2
#pragma unroll
        for (int i = 0; i < 4; i++) {
            const int growb = row0 + wm * 64 + i * 16 + quad * 4;
#pragma unroll
            for (int r = 0; r < 4; r++) {
                const float inv = 1.0f / rowsum[(long)bz * M + growb + r];
#pragma unroll
                for (int j = 0; j < 4; j++) {
                    const int gcol = col0 + wn * 64 + j * 16 + lr;
                    ((float*)Cout)[cbase + (long)(growb + r) * N + gcol] =
                        acc[i][j][r] * inv;
                }
            }
        }
    }
}

// ---------------------------------------------------------------------------
// Verbatim R4 128x128 engine -- used for the att GEMM (512 blocks = 2/CU).
// ---------------------------------------------------------------------------
template <int MODE>
__global__ void gemm128_kernel(const unsigned short* __restrict__ A,
                               const unsigned short* __restrict__ Bt,
                               const float* __restrict__ bias0,
                               const float* __restrict__ bias1,
                               float* __restrict__ rowsum,
                               void* __restrict__ Cout,
                               int M, int N, int K,
                               float scale,
                               long sA, long sB, long sC) {
    __shared__ __align__(16) unsigned short As[128 * 64];
    __shared__ __align__(16) unsigned short Bs[128 * 64];

    int bx, by, bz;
    {
        const int nx = gridDim.x;
        const int Rt = gridDim.y * gridDim.z;
        if ((Rt & 7) == 0) {
            int flat = ((int)blockIdx.z * gridDim.y + blockIdx.y) * nx + blockIdx.x;
            int rpx = Rt >> 3;
            int c = flat & 7;
            int j = flat >> 3;
            bx = j / rpx;
            int yg = c * rpx + (j - bx * rpx);
            bz = yg / gridDim.y;
            by = yg - bz * gridDim.y;
        } else {
            bx = blockIdx.x; by = blockIdx.y; bz = blockIdx.z;
        }
    }

    A  += (long)bz * sA;
    Bt += (long)bz * sB;

    const int t = threadIdx.x;
    const int lane = t & 63;
    const int wave = t >> 6;
    const int wm = wave >> 1, wn = wave & 1;
    const int row0 = by * 128;
    const int col0 = bx * 128;

    const int rS = lane >> 3;
    const int kOffS = ((lane & 7) ^ rS) * 8;
    const unsigned short* gA[4];
    const unsigned short* gB[4];
    unsigned short* lA[4];
    unsigned short* lB[4];
#pragma unroll
    for (int i = 0; i < 4; i++) {
        const int rowl = i * 32 + wave * 8 + rS;
        const int ldsrow = i * 32 + wave * 8;
        gA[i] = A  + (long)(row0 + rowl) * K + kOffS;
        gB[i] = Bt + (long)(col0 + rowl) * K + kOffS;
        lA[i] = As + ldsrow * 64;
        lB[i] = Bs + ldsrow * 64;
    }

    const int lr = lane & 15;
    const int quad = lane >> 4;
    const int pc0 = (quad ^ (lr & 7)) * 8;
    const int pc1 = ((4 + quad) ^ (lr & 7)) * 8;

    f32x4 acc[4][4];
#pragma unroll
    for (int i = 0; i < 4; i++)
#pragma unroll
        for (int j = 0; j < 4; j++) acc[i][j] = f32x4{0.f, 0.f, 0.f, 0.f};

    for (int k0 = 0; k0 < K; k0 += 64) {
#pragma unroll
        for (int i = 0; i < 4; i++) {
            load16_to_lds(gA[i] + k0, lA[i]);
            load16_to_lds(gB[i] + k0, lB[i]);
        }
        __syncthreads();

#pragma unroll
        for (int ks = 0; ks < 2; ks++) {
            const int pc = ks ? pc1 : pc0;
            bf16x8 a[4], b[4];
#pragma unroll
            for (int i = 0; i < 4; i++) {
                a[i] = __builtin_bit_cast(bf16x8,
                    *(const short8*)(As + (wm * 64 + i * 16 + lr) * 64 + pc));
                b[i] = __builtin_bit_cast(bf16x8,
                    *(const short8*)(Bs + (wn * 64 + i * 16 + lr) * 64 + pc));
            }
#pragma unroll
            for (int i = 0; i < 4; i++)
#pragma unroll
                for (int j = 0; j < 4; j++)
                    acc[i][j] = __builtin_amdgcn_mfma_f32_16x16x32_bf16(
                        a[i], b[j], acc[i][j], 0, 0, 0);
        }
        __syncthreads();
    }

    const long cbase = (long)bz * sC;

    if (MODE == 0) {
        const float* bp = (bz && bias1) ? bias1 : bias0;
#pragma unroll
        for (int j = 0; j < 4; j++) {
            const int gcol = col0 + wn * 64 + j * 16 + lr;
            const float bv = bp[gcol];
#pragma unroll
            for (int i = 0; i < 4; i++) {
                const int growb = row0 + wm * 64 + i * 16 + quad * 4;
#pragma unroll
                for (int r = 0; r < 4; r++) {
                    float val = acc[i][j][r] * scale + bv;
                    ((unsigned short*)Cout)[cbase + (long)(growb + r) * N + gcol] = f2b(val);
                }
            }
        }
    } else if (MODE == 1) {
        float psum[4][4];
#pragma unroll
        for (int i = 0; i < 4; i++)
#pragma unroll
            for (int r = 0; r < 4; r++) psum[i][r] = 0.f;
#pragma unroll
        for (int j = 0; j < 4; j++) {
            const int gcol = col0 + wn * 64 + j * 16 + lr;
#pragma unroll
            for (int i = 0; i < 4; i++) {
                const int growb = row0 + wm * 64 + i * 16 + quad * 4;
#pragma unroll
                for (int r = 0; r < 4; r++) {
                    float e = __expf(acc[i][j][r] * scale);
                    psum[i][r] += e;
                    ((unsigned short*)Cout)[cbase + (long)(growb + r) * N + gcol] = f2b(e);
                }
            }
        }
#pragma unroll
        for (int i = 0; i < 4; i++)
#pragma unroll
            for (int r = 0; r < 4; r++) {
                float s = psum[i][r];
                s += __shfl_xor(s, 1);
                s += __shfl_xor(s, 2);
                s += __shfl_xor(s, 4);
                s += __shfl_xor(s, 8);
                if (lr == 0) {
                    const int grow = row0 + wm * 64 + i * 16 + quad * 4 + r;
                    atomicAdd(rowsum + (long)bz * M + grow, s);
                }
            }
    } else {  // MODE == 2
#pragma unroll
        for (int i = 0; i < 4; i++) {
            const int growb = row0 + wm * 64 + i * 16 + quad * 4;
#pragma unroll
            for (int r = 0; r < 4; r++) {
                const float inv = 1.0f / rowsum[(long)bz * M + growb + r];
#pragma unroll
                for (int j = 0; j < 4; j++) {
                    const int gcol = col0 + wn * 64 + j * 16 + lr;
                    ((float*)Cout)[cbase + (long)(growb + r) * N + gcol] =
                        acc[i][j][r] * inv;
                }
            }
        }
    }
}

// ---------------------------------------------------------------------------
extern "C" void kernel_launch(void* const* d_in, const int* in_sizes, int n_in,
                              void* d_out, int out_size, void* d_ws, size_t ws_size,
                              hipStream_t stream) {
    const float* q   = (const float*)d_in[0];
    const float* k   = (const float*)d_in[1];
    const float* v   = (const float*)d_in[2];
    const float* W1w = (const float*)d_in[3];
    const float* W1b = (const float*)d_in[4];
    const float* W2w = (const float*)d_in[5];
    const float* W2b = (const float*)d_in[6];
    float* out = (float*)d_out;

    const int B = 4, SQ = 2048, SK = 2048, D = 1024, U = 1024;
    char* ws = (char*)d_ws;
    const size_t MB = 1024 * 1024;
    unsigned short* qbf = (unsigned short*)(ws + 0);        // 16 MB
    unsigned short* kbf = (unsigned short*)(ws + 16 * MB);  // 16 MB
    unsigned short* vT  = (unsigned short*)(ws + 32 * MB);  // 16 MB [B][D][SK]
    unsigned short* W1t = (unsigned short*)(ws + 48 * MB);  // 2 MB  [U][D]
    unsigned short* W2t = (unsigned short*)(ws + 50 * MB);  // 2 MB
    unsigned short* l1  = (unsigned short*)(ws + 52 * MB);  // 16 MB [B*SQ][U]
    unsigned short* l2  = (unsigned short*)(ws + 68 * MB);  // 16 MB
    unsigned short* sc  = (unsigned short*)(ws + 0);        // 32 MB [B][SQ][SK]

    // rowsum: prefer a fresh slot at 84 MB (zeroed inside prep -> no memset
    // dispatch). Fallback if the workspace is too small: reuse the W2t slot
    // (dead after l1l2) and memset between l1l2 and score, as in R8.
    float* rowsum;
    bool prep_zeroes_rowsum;
    if (ws_size >= 85 * MB) {
        rowsum = (float*)(ws + 84 * MB);
        prep_zeroes_rowsum = true;
    } else {
        rowsum = (float*)(ws + 50 * MB);
        prep_zeroes_rowsum = false;
    }

    // 1: all preprocessing (q/k cast, v/W1/W2 transpose, rowsum zero)
    prep_kernel<<<dim3(64, 32, 10), 256, 0, stream>>>(
        q, k, v, W1w, W2w, qbf, kbf, vT, W1t, W2t,
        prep_zeroes_rowsum ? rowsum : nullptr);
    // 2: merged l1 = q@W1+b1 (bz=0), l2 = k@W2+b2 (bz=1)  (bf16 out)
    gemm256_kernel<0><<<dim3(U / 128, (B * SQ) / 256, 2), 512, 0, stream>>>(
        qbf, W1t, W1b, W2b, nullptr, l1, B * SQ, U, D, 1.0f,
        (long)8 * 1024 * 1024, (long)1024 * 1024, (long)8 * 1024 * 1024);
    // 3 (fallback only): zero rowsum in the W2t slot after l1l2 read it
    if (!prep_zeroes_rowsum)
        hipMemsetAsync(rowsum, 0, (size_t)B * SQ * sizeof(float), stream);
    // 4: sc = exp(l1 @ l2^T / sqrt(SK)) bf16 + rowsum atomics
    const float invs = 1.0f / sqrtf((float)SK);
    gemm256_kernel<1><<<dim3(SK / 128, SQ / 256, B), 512, 0, stream>>>(
        l1, l2, nullptr, nullptr, rowsum, sc, SQ, SK, U, invs,
        (long)SQ * U, (long)SK * U, (long)SQ * SK);
    // 5: att = (sc @ vT^T) / rowsum[row]  (fp32 out) -- proven 128^2 engine
    gemm128_kernel<2><<<dim3(D / 128, SQ / 128, B), 256, 0, stream>>>(
        sc, vT, nullptr, nullptr, rowsum, out, SQ, D, SK, 1.0f,
        (long)SQ * SK, (long)D * SK, (long)SQ * D);
}

// Round 6
// 261.678 us; speedup vs baseline: 1.1395x; 1.0147x over previous
//
#include <hip/hip_runtime.h>
#include <cmath>
#include <stdint.h>

// ---------------------------------------------------------------------------
// AttentionLayer: att = softmax((q@W1+b1) @ (k@W2+b2)^T / sqrt(Sk)) @ v
// B=4, SQ=SK=2048, D=UNITS=1024, fp32 in/out, bf16 MFMA internally.
// R10: q/k cast slices DELETED from prep; l1l2 GEMM casts A in-flight
//      (fp32 global -> v_cvt_pk_bf16_f32 -> ds_write_b128, B stays on
//      global_load_lds). Prep = v/W transpose + rowsum zero only.
//      score (256x128) and att (128^2) engines byte-frozen from R8/R9.
// ---------------------------------------------------------------------------

typedef short short8 __attribute__((ext_vector_type(8)));
typedef float f32x4 __attribute__((ext_vector_type(4)));
typedef __bf16 bf16x8 __attribute__((ext_vector_type(8)));
typedef unsigned int u32x4 __attribute__((ext_vector_type(4)));

typedef __attribute__((address_space(3))) void lds_void;
typedef __attribute__((address_space(1))) void gbl_void;

__device__ __forceinline__ unsigned short f2b(float x) {
    unsigned u = __builtin_bit_cast(unsigned, x);
    u += 0x7fffu + ((u >> 16) & 1u);
    return (unsigned short)(u >> 16);
}

// ---------------------------------------------------------------------------
// Slim prep: z = 0..3 v-batch transpose (64x64 tiles), z=4 W1 transpose
// (+ rowsum zero stowaway), z=5 W2 transpose.  grid (64, 8, 6) x 256 thr.
// ---------------------------------------------------------------------------
__global__ void prep_kernel(const float* __restrict__ v,
                            const float* __restrict__ W1,
                            const float* __restrict__ W2,
                            unsigned short* __restrict__ vT,
                            unsigned short* __restrict__ W1t,
                            unsigned short* __restrict__ W2t,
                            float* __restrict__ rs) {
    const int bz = blockIdx.z;
    const int t = threadIdx.x;
    const int tid2 = blockIdx.y * 64 + blockIdx.x;   // 0..511

    // ---- rowsum-zero stowaway: 32 blocks of the z=4 slice ----
    if (bz == 4 && tid2 >= 256 && tid2 < 288) {
        if (rs) rs[(tid2 - 256) * 256 + t] = 0.f;
        return;
    }

    __shared__ float tile[64][65];
    const float* in;
    unsigned short* out;
    int R, C;
    if (bz < 4) {
        R = 2048; C = 1024;                 // v: 32 row-tiles x 16 col-tiles
        in = v + (long)bz * R * C;
        out = vT + (long)bz * R * C;
    } else {
        R = 1024; C = 1024;                 // W: 16 x 16 tiles
        if (tid2 >= 256) return;
        in = (bz == 4) ? W1 : W2;
        out = (bz == 4) ? W1t : W2t;
    }
    const int rt = (tid2 >> 4) * 64;
    const int ct = (tid2 & 15) * 64;

    {
        const int rr = t >> 2;              // 0..63
        const int cb = (t & 3) * 16;        // 0,16,32,48
        const float* src = in + (long)(rt + rr) * C + ct + cb;
#pragma unroll
        for (int u = 0; u < 4; u++) {
            float4 a = *(const float4*)(src + 4 * u);
            tile[rr][cb + 4 * u + 0] = a.x;
            tile[rr][cb + 4 * u + 1] = a.y;
            tile[rr][cb + 4 * u + 2] = a.z;
            tile[rr][cb + 4 * u + 3] = a.w;
        }
    }
    __syncthreads();
    {
        const int cc = t >> 2;              // 0..63
        const int rb = (t & 3) * 16;        // 0,16,32,48
        unsigned short* dst = out + (long)(ct + cc) * R + rt + rb;
#pragma unroll
        for (int u = 0; u < 2; u++) {
            union { short8 v8; unsigned short us[8]; } o;
#pragma unroll
            for (int e = 0; e < 8; e++) o.us[e] = f2b(tile[rb + 8 * u + e][cc]);
            *(short8*)(dst + 8 * u) = o.v8;
        }
    }
}

__device__ __forceinline__ void load16_to_lds(const unsigned short* g,
                                              unsigned short* l) {
    __builtin_amdgcn_global_load_lds((gbl_void*)g, (lds_void*)l, 16, 0, 0);
}

// ---------------------------------------------------------------------------
// 256x128 bf16 GEMM: C[M][N] = A[M][K] * Bt[N][K]^T, BK=64 (48 KB LDS),
// 512 thr = 8 waves (4Mx2N), each wave 4x4 of 16x16x32 MFMA per sub-k.
// LDS XOR swizzle (phys chunk = logical ^ (row&7)); XCD-stripe block remap.
// Single-buffered 2-barrier loop; latency hidden by 2 blocks/CU residency.
// CASTA=1: A is fp32 (Afq for bz=0, Afk for bz=1), reg-staged with
//          v_cvt_pk_bf16_f32 (RTNE == f2b) + ds_write_b128.
// MODE 0: bf16 out, + bias (bias1 used when bz==1 -- merged l1/l2)
// MODE 1: bf16 out = exp(acc*scale), atomicAdd per-row sums into rowsum
// ---------------------------------------------------------------------------
template <int MODE, int CASTA>
__global__ __launch_bounds__(512, 4) void gemm256_kernel(
                               const unsigned short* __restrict__ A,
                               const unsigned short* __restrict__ Bt,
                               const float* __restrict__ bias0,
                               const float* __restrict__ bias1,
                               float* __restrict__ rowsum,
                               void* __restrict__ Cout,
                               int M, int N, int K,
                               float scale,
                               long sA, long sB, long sC,
                               const float* __restrict__ Afq,
                               const float* __restrict__ Afk) {
    __shared__ __align__(16) unsigned short As[256 * 64];  // 32 KB
    __shared__ __align__(16) unsigned short Bs[128 * 64];  // 16 KB

    // ---- XCD-aware tile remap (bijective) ----
    int bx, by, bz;
    {
        const int nx = gridDim.x;
        const int Rt = gridDim.y * gridDim.z;
        if ((Rt & 7) == 0) {
            int flat = ((int)blockIdx.z * gridDim.y + blockIdx.y) * nx + blockIdx.x;
            int rpx = Rt >> 3;
            int c = flat & 7;
            int j = flat >> 3;
            bx = j / rpx;
            int yg = c * rpx + (j - bx * rpx);
            bz = yg / gridDim.y;
            by = yg - bz * gridDim.y;
        } else {
            bx = blockIdx.x; by = blockIdx.y; bz = blockIdx.z;
        }
    }

    Bt += (long)bz * sB;

    const int t = threadIdx.x;
    const int lane = t & 63;
    const int wave = t >> 6;               // 0..7
    const int wm = wave >> 1, wn = wave & 1;  // 4M x 2N
    const int row0 = by * 256;
    const int col0 = bx * 128;

    // staging: lane l -> row group l>>3 (8 rows/issue), phys chunk l&7;
    // source chunk XOR'd so phys = logical ^ (row&7)
    const int rS = lane >> 3;
    const int kOffS = ((lane & 7) ^ rS) * 8;
    const unsigned short* gA[4];
    const float* fA[4];
    unsigned short* lA[4];
    const unsigned short* gB[2];
    unsigned short* lB[2];
#pragma unroll
    for (int i = 0; i < 4; i++) {
        const int rowl = wave * 32 + i * 8;
        lA[i] = As + rowl * 64;
        if (CASTA) {
            const float* Af = bz ? Afk : Afq;
            fA[i] = Af + (long)(row0 + rowl + rS) * K + kOffS;
        } else {
            gA[i] = A + (long)bz * sA + (long)(row0 + rowl + rS) * K + kOffS;
        }
    }
#pragma unroll
    for (int i = 0; i < 2; i++) {
        const int rowl = wave * 16 + i * 8;
        gB[i] = Bt + (long)(col0 + rowl + rS) * K + kOffS;
        lB[i] = Bs + rowl * 64;
    }

    const int lr = lane & 15;
    const int quad = lane >> 4;
    const int pc0 = (quad ^ (lr & 7)) * 8;
    const int pc1 = ((4 + quad) ^ (lr & 7)) * 8;

    f32x4 acc[4][4];
#pragma unroll
    for (int i = 0; i < 4; i++)
#pragma unroll
        for (int j = 0; j < 4; j++) acc[i][j] = f32x4{0.f, 0.f, 0.f, 0.f};

    for (int k0 = 0; k0 < K; k0 += 64) {
#pragma unroll
        for (int i = 0; i < 2; i++) load16_to_lds(gB[i] + k0, lB[i]);
        if (CASTA) {
            // reg-stage A: fp32 -> bf16 (RTNE cvt_pk) -> LDS, same layout
            // as the gload_lds path (base + lane*16B).
#pragma unroll
            for (int i = 0; i < 4; i++) {
                const float* s = fA[i] + k0;
                float4 x = *(const float4*)(s);
                float4 y = *(const float4*)(s + 4);
                unsigned w0, w1, w2, w3;
                asm("v_cvt_pk_bf16_f32 %0, %1, %2" : "=v"(w0) : "v"(x.x), "v"(x.y));
                asm("v_cvt_pk_bf16_f32 %0, %1, %2" : "=v"(w1) : "v"(x.z), "v"(x.w));
                asm("v_cvt_pk_bf16_f32 %0, %1, %2" : "=v"(w2) : "v"(y.x), "v"(y.y));
                asm("v_cvt_pk_bf16_f32 %0, %1, %2" : "=v"(w3) : "v"(y.z), "v"(y.w));
                *(u32x4*)(lA[i] + lane * 8) = u32x4{w0, w1, w2, w3};
            }
        } else {
#pragma unroll
            for (int i = 0; i < 4; i++) load16_to_lds(gA[i] + k0, lA[i]);
        }
        __syncthreads();

#pragma unroll
        for (int ks = 0; ks < 2; ks++) {
            const int pc = ks ? pc1 : pc0;
            bf16x8 a[4], b[4];
#pragma unroll
            for (int i = 0; i < 4; i++) {
                a[i] = __builtin_bit_cast(bf16x8,
                    *(const short8*)(As + (wm * 64 + i * 16 + lr) * 64 + pc));
                b[i] = __builtin_bit_cast(bf16x8,
                    *(const short8*)(Bs + (wn * 64 + i * 16 + lr) * 64 + pc));
            }
#pragma unroll
            for (int i = 0; i < 4; i++)
#pragma unroll
                for (int j = 0; j < 4; j++)
                    acc[i][j] = __builtin_amdgcn_mfma_f32_16x16x32_bf16(
                        a[i], b[j], acc[i][j], 0, 0, 0);
        }
        __syncthreads();
    }

    // ---- epilogue (C/D layout: col = lane&15, row = quad*4 + reg) ----
    const long cbase = (long)bz * sC;

    if (MODE == 0) {
        const float* bp = (bz && bias1) ? bias1 : bias0;
#pragma unroll
        for (int j = 0; j < 4; j++) {
            const int gcol = col0 + wn * 64 + j * 16 + lr;
            const float bv = bp[gcol];
#pragma unroll
            for (int i = 0; i < 4; i++) {
                const int growb = row0 + wm * 64 + i * 16 + quad * 4;
#pragma unroll
                for (int r = 0; r < 4; r++) {
                    float val = acc[i][j][r] * scale + bv;
                    ((unsigned short*)Cout)[cbase + (long)(growb + r) * N + gcol] = f2b(val);
                }
            }
        }
    } else {  // MODE == 1
        float psum[4][4];
#pragma unroll
        for (int i = 0; i < 4; i++)
#pragma unroll
            for (int r = 0; r < 4; r++) psum[i][r] = 0.f;
#pragma unroll
        for (int j = 0; j < 4; j++) {
            const int gcol = col0 + wn * 64 + j * 16 + lr;
#pragma unroll
            for (int i = 0; i < 4; i++) {
                const int growb = row0 + wm * 64 + i * 16 + quad * 4;
#pragma unroll
                for (int r = 0; r < 4; r++) {
                    float e = __expf(acc[i][j][r] * scale);
                    psum[i][r] += e;
                    ((unsigned short*)Cout)[cbase + (long)(growb + r) * N + gcol] = f2b(e);
                }
            }
        }
        // reduce across the 16 lr lanes (xor masks 1,2,4,8 keep quad bits)
#pragma unroll
        for (int i = 0; i < 4; i++)
#pragma unroll
            for (int r = 0; r < 4; r++) {
                float s = psum[i][r];
                s += __shfl_xor(s, 1);
                s += __shfl_xor(s, 2);
                s += __shfl_xor(s, 4);
                s += __shfl_xor(s, 8);
                if (lr == 0) {
                    const int grow = row0 + wm * 64 + i * 16 + quad * 4 + r;
                    atomicAdd(rowsum + (long)bz * M + grow, s);
                }
            }
    }
}

// ---------------------------------------------------------------------------
// Verbatim R4 128x128 engine -- used for the att GEMM (512 blocks = 2/CU).
// ---------------------------------------------------------------------------
template <int MODE>
__global__ void gemm128_kernel(const unsigned short* __restrict__ A,
                               const unsigned short* __restrict__ Bt,
                               const float* __restrict__ bias0,
                               const float* __restrict__ bias1,
                               float* __restrict__ rowsum,
                               void* __restrict__ Cout,
                               int M, int N, int K,
                               float scale,
                               long sA, long sB, long sC) {
    __shared__ __align__(16) unsigned short As[128 * 64];
    __shared__ __align__(16) unsigned short Bs[128 * 64];

    int bx, by, bz;
    {
        const int nx = gridDim.x;
        const int Rt = gridDim.y * gridDim.z;
        if ((Rt & 7) == 0) {
            int flat = ((int)blockIdx.z * gridDim.y + blockIdx.y) * nx + blockIdx.x;
            int rpx = Rt >> 3;
            int c = flat & 7;
            int j = flat >> 3;
            bx = j / rpx;
            int yg = c * rpx + (j - bx * rpx);
            bz = yg / gridDim.y;
            by = yg - bz * gridDim.y;
        } else {
            bx = blockIdx.x; by = blockIdx.y; bz = blockIdx.z;
        }
    }

    A  += (long)bz * sA;
    Bt += (long)bz * sB;

    const int t = threadIdx.x;
    const int lane = t & 63;
    const int wave = t >> 6;
    const int wm = wave >> 1, wn = wave & 1;
    const int row0 = by * 128;
    const int col0 = bx * 128;

    const int rS = lane >> 3;
    const int kOffS = ((lane & 7) ^ rS) * 8;
    const unsigned short* gA[4];
    const unsigned short* gB[4];
    unsigned short* lA[4];
    unsigned short* lB[4];
#pragma unroll
    for (int i = 0; i < 4; i++) {
        const int rowl = i * 32 + wave * 8 + rS;
        const int ldsrow = i * 32 + wave * 8;
        gA[i] = A  + (long)(row0 + rowl) * K + kOffS;
        gB[i] = Bt + (long)(col0 + rowl) * K + kOffS;
        lA[i] = As + ldsrow * 64;
        lB[i] = Bs + ldsrow * 64;
    }

    const int lr = lane & 15;
    const int quad = lane >> 4;
    const int pc0 = (quad ^ (lr & 7)) * 8;
    const int pc1 = ((4 + quad) ^ (lr & 7)) * 8;

    f32x4 acc[4][4];
#pragma unroll
    for (int i = 0; i < 4; i++)
#pragma unroll
        for (int j = 0; j < 4; j++) acc[i][j] = f32x4{0.f, 0.f, 0.f, 0.f};

    for (int k0 = 0; k0 < K; k0 += 64) {
#pragma unroll
        for (int i = 0; i < 4; i++) {
            load16_to_lds(gA[i] + k0, lA[i]);
            load16_to_lds(gB[i] + k0, lB[i]);
        }
        __syncthreads();

#pragma unroll
        for (int ks = 0; ks < 2; ks++) {
            const int pc = ks ? pc1 : pc0;
            bf16x8 a[4], b[4];
#pragma unroll
            for (int i = 0; i < 4; i++) {
                a[i] = __builtin_bit_cast(bf16x8,
                    *(const short8*)(As + (wm * 64 + i * 16 + lr) * 64 + pc));
                b[i] = __builtin_bit_cast(bf16x8,
                    *(const short8*)(Bs + (wn * 64 + i * 16 + lr) * 64 + pc));
            }
#pragma unroll
            for (int i = 0; i < 4; i++)
#pragma unroll
                for (int j = 0; j < 4; j++)
                    acc[i][j] = __builtin_amdgcn_mfma_f32_16x16x32_bf16(
                        a[i], b[j], acc[i][j], 0, 0, 0);
        }
        __syncthreads();
    }

    const long cbase = (long)bz * sC;

    if (MODE == 2) {
#pragma unroll
        for (int i = 0; i < 4; i++) {
            const int growb = row0 + wm * 64 + i * 16 + quad * 4;
#pragma unroll
            for (int r = 0; r < 4; r++) {
                const float inv = 1.0f / rowsum[(long)bz * M + growb + r];
#pragma unroll
                for (int j = 0; j < 4; j++) {
                    const int gcol = col0 + wn * 64 + j * 16 + lr;
                    ((float*)Cout)[cbase + (long)(growb + r) * N + gcol] =
                        acc[i][j][r] * inv;
                }
            }
        }
    }
}

// ---------------------------------------------------------------------------
extern "C" void kernel_launch(void* const* d_in, const int* in_sizes, int n_in,
                              void* d_out, int out_size, void* d_ws, size_t ws_size,
                              hipStream_t stream) {
    const float* q   = (const float*)d_in[0];
    const float* k   = (const float*)d_in[1];
    const float* v   = (const float*)d_in[2];
    const float* W1w = (const float*)d_in[3];
    const float* W1b = (const float*)d_in[4];
    const float* W2w = (const float*)d_in[5];
    const float* W2b = (const float*)d_in[6];
    float* out = (float*)d_out;

    const int B = 4, SQ = 2048, SK = 2048, D = 1024, U = 1024;
    char* ws = (char*)d_ws;
    const size_t MB = 1024 * 1024;
    unsigned short* vT  = (unsigned short*)(ws + 32 * MB);  // 16 MB [B][D][SK]
    unsigned short* W1t = (unsigned short*)(ws + 48 * MB);  // 2 MB  [U][D]
    unsigned short* W2t = (unsigned short*)(ws + 50 * MB);  // 2 MB
    unsigned short* l1  = (unsigned short*)(ws + 52 * MB);  // 16 MB [B*SQ][U]
    unsigned short* l2  = (unsigned short*)(ws + 68 * MB);  // 16 MB
    unsigned short* sc  = (unsigned short*)(ws + 0);        // 32 MB [B][SQ][SK]

    // rowsum: fresh slot at 84 MB, zeroed inside prep (no memset dispatch);
    // fallback: W2t slot + memset between l1l2 and score.
    float* rowsum;
    bool prep_zeroes_rowsum;
    if (ws_size >= 85 * MB) {
        rowsum = (float*)(ws + 84 * MB);
        prep_zeroes_rowsum = true;
    } else {
        rowsum = (float*)(ws + 50 * MB);
        prep_zeroes_rowsum = false;
    }

    // 1: prep (v/W transposes + rowsum zero) -- q/k casts now in-GEMM
    prep_kernel<<<dim3(64, 8, 6), 256, 0, stream>>>(
        v, W1w, W2w, vT, W1t, W2t,
        prep_zeroes_rowsum ? rowsum : nullptr);
    // 2: merged l1 = q@W1+b1 (bz=0), l2 = k@W2+b2 (bz=1); A cast in-flight
    gemm256_kernel<0, 1><<<dim3(U / 128, (B * SQ) / 256, 2), 512, 0, stream>>>(
        nullptr, W1t, W1b, W2b, nullptr, l1, B * SQ, U, D, 1.0f,
        0, (long)1024 * 1024, (long)8 * 1024 * 1024, q, k);
    // 3 (fallback only): zero rowsum in the W2t slot after l1l2 read it
    if (!prep_zeroes_rowsum)
        hipMemsetAsync(rowsum, 0, (size_t)B * SQ * sizeof(float), stream);
    // 4: sc = exp(l1 @ l2^T / sqrt(SK)) bf16 + rowsum atomics
    const float invs = 1.0f / sqrtf((float)SK);
    gemm256_kernel<1, 0><<<dim3(SK / 128, SQ / 256, B), 512, 0, stream>>>(
        l1, l2, nullptr, nullptr, rowsum, sc, SQ, SK, U, invs,
        (long)SQ * U, (long)SK * U, (long)SQ * SK, nullptr, nullptr);
    // 5: att = (sc @ vT^T) / rowsum[row]  (fp32 out) -- proven 128^2 engine
    gemm128_kernel<2><<<dim3(D / 128, SQ / 128, B), 256, 0, stream>>>(
        sc, vT, nullptr, nullptr, rowsum, out, SQ, D, SK, 1.0f,
        (long)SQ * SK, (long)D * SK, (long)SQ * D);
}